// Round 14
// baseline (654.802 us; speedup 1.0000x reference)
//
#include <hip/hip_runtime.h>

#define NNODES 50000
#define NEDGES 800000
#define HDIM 128
#define DOUT 64
#define NLAYERS 3
#define NEG_SLOPE 0.2f
#define BSLICE 6250                                // node-range per bucket dim

#define NODE_OUT_ELEMS (NNODES * DOUT)             // 3,200,000
#define EDGE_OUT_ELEMS (NEDGES * 3)                // 2,400,000
#define GEMB_OFF (NODE_OUT_ELEMS + EDGE_OUT_ELEMS) // 5,600,000

typedef __attribute__((ext_vector_type(8))) short short8;
typedef __attribute__((ext_vector_type(4))) float f32x4;
typedef unsigned long long u64;

__device__ __forceinline__ float bf2f(unsigned short u) {
    union { unsigned int i; float f; } v; v.i = ((unsigned int)u) << 16; return v.f;
}
__device__ __forceinline__ unsigned short f2bf(float f) {
    union { unsigned int i; float f; } v; v.f = f;
    unsigned int b = v.i;
    unsigned int r = (b + 0x7FFFu + ((b >> 16) & 1u)) >> 16;
    return (unsigned short)r;
}
__device__ __forceinline__ float leaky(float x) { return x > 0.f ? x : NEG_SLOPE * x; }
__device__ __forceinline__ float wread(const void* p, size_t i, int f32) {
    return f32 ? ((const float*)p)[i] : bf2f(((const unsigned short*)p)[i]);
}
__device__ __forceinline__ int eget(const int* e32, const int* iflag, int which, int e) {
    int idx = which * NEDGES + e;
    return (*iflag) ? e32[idx] : e32[2 * idx];
}

// Zero cnt, cur, gsum, flags in one launch.
__global__ void init_kernel(int* cnt, int* cur, float* gsum, int* flags) {
    int i = blockIdx.x * 256 + threadIdx.x;
    if (i < NNODES) { cnt[i] = 0; cur[i] = 0; }
    if (blockIdx.x == 0) {
        if (threadIdx.x < HDIM) gsum[threadIdx.x] = 0.f;
        if (threadIdx.x < 2) flags[threadIdx.x] = 0;
    }
}

// block 0: sampled f32 detect on x; block 1: sampled i64 detect on edges.
__global__ void detect_kernel(const unsigned short* xb, const int* e32,
                              int* fflag, int* iflag) {
    if (blockIdx.x == 0) {
        int hit = 0;
        for (int j = threadIdx.x; j < 4096; j += 256) {
            int e = (xb[j] >> 7) & 0xFF;
            if (e >= 0x90) hit = 1;
        }
        if (hit) atomicOr(fflag, 1);
    } else {
        int hit = 0;
        for (int t = threadIdx.x; t < 16384; t += 256) {
            int i = t * 48;
            if (e32[2 * i + 1] != 0) hit = 1;
        }
        if (__any(hit)) {
            if ((threadIdx.x & 63) == 0) atomicOr(iflag, 1);
        }
    }
}

// ---------------------------------------------------------------------------
// MFMA GEMM, N=128 (+ fused alpha for layer GEMMs). Round-11 proven.
// ---------------------------------------------------------------------------
__global__ __launch_bounds__(256) void gemm_mfma_kernel(
    const void* __restrict__ Av, int a_from_x, const void* __restrict__ Bw,
    size_t b_off, const void* __restrict__ bias, unsigned short* __restrict__ C,
    int M, int relu, const int* __restrict__ f32flag,
    float* __restrict__ alpha_s, float* __restrict__ alpha_d,
    const void* __restrict__ gat_as, const void* __restrict__ gat_ad, int aoff)
{
    constexpr int KP = 128 + 8;
    __shared__ unsigned short sA[64 * KP];
    __shared__ float pS[64][4], pD[64][4];
    const int f32 = *f32flag;
    const int tid = threadIdx.x;
    const int row0 = blockIdx.x * 64;

    if (a_from_x && f32) {
        const float* Af = (const float*)Av;
        for (int c = tid; c < 64 * 16; c += 256) {
            int r = c >> 4, cp = c & 15;
            int gr = row0 + r;
            unsigned short o[8] = {0, 0, 0, 0, 0, 0, 0, 0};
            if (gr < M) {
                float4 v0 = *(const float4*)(Af + (size_t)gr * 128 + cp * 8);
                float4 v1 = *(const float4*)(Af + (size_t)gr * 128 + cp * 8 + 4);
                o[0] = f2bf(v0.x); o[1] = f2bf(v0.y); o[2] = f2bf(v0.z); o[3] = f2bf(v0.w);
                o[4] = f2bf(v1.x); o[5] = f2bf(v1.y); o[6] = f2bf(v1.z); o[7] = f2bf(v1.w);
            }
            *(uint4*)(&sA[r * KP + cp * 8]) = *(uint4*)o;
        }
    } else {
        const unsigned short* A = (const unsigned short*)Av;
        for (int c = tid; c < 64 * 16; c += 256) {
            int r = c >> 4, cp = c & 15;
            int gr = row0 + r;
            uint4 v = {0u, 0u, 0u, 0u};
            if (gr < M) v = *(const uint4*)(A + (size_t)gr * 128 + cp * 8);
            *(uint4*)(&sA[r * KP + cp * 8]) = v;
        }
    }
    __syncthreads();

    const int wave = tid >> 6, lane = tid & 63;
    const int quad = lane >> 4, l15 = lane & 15;
    const int ncol0 = wave * 32;

    short8 bw[4][2];
    #pragma unroll
    for (int kk = 0; kk < 4; kk++)
        #pragma unroll
        for (int nt = 0; nt < 2; nt++) {
            int n = ncol0 + nt * 16 + l15;
            short8 t;
            #pragma unroll
            for (int j = 0; j < 8; j++)
                t[j] = (short)f2bf(wread(Bw, b_off + (size_t)(kk * 32 + quad * 8 + j) * 128 + n, f32));
            bw[kk][nt] = t;
        }

    float bv[2];
    #pragma unroll
    for (int nt = 0; nt < 2; nt++)
        bv[nt] = bias ? wread(bias, ncol0 + nt * 16 + l15, f32) : 0.f;

    f32x4 acc[4][2];
    #pragma unroll
    for (int mt = 0; mt < 4; mt++)
        #pragma unroll
        for (int nt = 0; nt < 2; nt++) {
            acc[mt][nt][0] = bv[nt]; acc[mt][nt][1] = bv[nt];
            acc[mt][nt][2] = bv[nt]; acc[mt][nt][3] = bv[nt];
        }

    #pragma unroll
    for (int kk = 0; kk < 4; kk++) {
        short8 a[4];
        #pragma unroll
        for (int mt = 0; mt < 4; mt++)
            a[mt] = *(const short8*)(&sA[(mt * 16 + l15) * KP + kk * 32 + quad * 8]);
        #pragma unroll
        for (int mt = 0; mt < 4; mt++)
            #pragma unroll
            for (int nt = 0; nt < 2; nt++)
                acc[mt][nt] = __builtin_amdgcn_mfma_f32_16x16x32_bf16(
                    a[mt], bw[kk][nt], acc[mt][nt], 0, 0, 0);
    }

    if (alpha_s) {
        float as0 = wread(gat_as, (size_t)aoff + ncol0 + l15, f32);
        float as1 = wread(gat_as, (size_t)aoff + ncol0 + 16 + l15, f32);
        float ad0 = wread(gat_ad, (size_t)aoff + ncol0 + l15, f32);
        float ad1 = wread(gat_ad, (size_t)aoff + ncol0 + 16 + l15, f32);
        #pragma unroll
        for (int mt = 0; mt < 4; mt++)
            #pragma unroll
            for (int q = 0; q < 4; q++) {
                float vs = acc[mt][0][q] * as0 + acc[mt][1][q] * as1;
                float vd = acc[mt][0][q] * ad0 + acc[mt][1][q] * ad1;
                #pragma unroll
                for (int d = 1; d < 16; d <<= 1) {
                    vs += __shfl_xor(vs, d);
                    vd += __shfl_xor(vd, d);
                }
                if (l15 == 0) {
                    int r = mt * 16 + quad * 4 + q;
                    pS[r][wave] = vs; pD[r][wave] = vd;
                }
            }
        __syncthreads();
        if (tid < 64) {
            int row = row0 + tid;
            if (row < M) {
                alpha_s[row] = pS[tid][0] + pS[tid][1] + pS[tid][2] + pS[tid][3];
                alpha_d[row] = pD[tid][0] + pD[tid][1] + pD[tid][2] + pD[tid][3];
            }
        }
    }

    #pragma unroll
    for (int mt = 0; mt < 4; mt++)
        #pragma unroll
        for (int nt = 0; nt < 2; nt++)
            #pragma unroll
            for (int q = 0; q < 4; q++) {
                int row = row0 + mt * 16 + quad * 4 + q;
                if (row < M) {
                    float v = acc[mt][nt][q];
                    if (relu) v = fmaxf(v, 0.f);
                    C[(size_t)row * 128 + ncol0 + nt * 16 + l15] = f2bf(v);
                }
            }
}

// ---------------------------------------------------------------------------
// Fused node MLP (+ gsum). Round-11 proven. Runs LAST (h intact).
// ---------------------------------------------------------------------------
__global__ __launch_bounds__(256) void node_mlp_kernel(
    const unsigned short* __restrict__ h, const void* __restrict__ Wn1,
    const void* __restrict__ bn1, const void* __restrict__ Wn2,
    const void* __restrict__ bn2, float* __restrict__ out,
    float* __restrict__ gsum, int M, const int* __restrict__ f32flag)
{
    constexpr int KP = 128 + 8;
    __shared__ unsigned short sA[64 * KP];
    const int f32 = *f32flag;
    const int tid = threadIdx.x;
    const int row0 = blockIdx.x * 64;

    for (int c = tid; c < 64 * 16; c += 256) {
        int r = c >> 4, cp = c & 15;
        int gr = row0 + r;
        uint4 v = {0u, 0u, 0u, 0u};
        if (gr < M) v = *(const uint4*)(h + (size_t)gr * 128 + cp * 8);
        *(uint4*)(&sA[r * KP + cp * 8]) = v;
    }
    __syncthreads();

    if (tid < 128) {
        float hs = 0.f;
        for (int r = 0; r < 64; r++) hs += bf2f(sA[r * KP + tid]);
        atomicAdd(&gsum[tid], hs);
    }

    const int wave = tid >> 6, lane = tid & 63;
    const int quad = lane >> 4, l15 = lane & 15;
    const int ncol0 = wave * 32;

    {
        short8 bw[4][2];
        #pragma unroll
        for (int kk = 0; kk < 4; kk++)
            #pragma unroll
            for (int nt = 0; nt < 2; nt++) {
                int n = ncol0 + nt * 16 + l15;
                short8 t;
                #pragma unroll
                for (int j = 0; j < 8; j++)
                    t[j] = (short)f2bf(wread(Wn1, (size_t)(kk * 32 + quad * 8 + j) * 128 + n, f32));
                bw[kk][nt] = t;
            }
        float bv[2];
        #pragma unroll
        for (int nt = 0; nt < 2; nt++)
            bv[nt] = wread(bn1, ncol0 + nt * 16 + l15, f32);

        f32x4 acc[4][2];
        #pragma unroll
        for (int mt = 0; mt < 4; mt++)
            #pragma unroll
            for (int nt = 0; nt < 2; nt++) {
                acc[mt][nt][0] = bv[nt]; acc[mt][nt][1] = bv[nt];
                acc[mt][nt][2] = bv[nt]; acc[mt][nt][3] = bv[nt];
            }
        #pragma unroll
        for (int kk = 0; kk < 4; kk++) {
            short8 a[4];
            #pragma unroll
            for (int mt = 0; mt < 4; mt++)
                a[mt] = *(const short8*)(&sA[(mt * 16 + l15) * KP + kk * 32 + quad * 8]);
            #pragma unroll
            for (int mt = 0; mt < 4; mt++)
                #pragma unroll
                for (int nt = 0; nt < 2; nt++)
                    acc[mt][nt] = __builtin_amdgcn_mfma_f32_16x16x32_bf16(
                        a[mt], bw[kk][nt], acc[mt][nt], 0, 0, 0);
        }
        __syncthreads();
        #pragma unroll
        for (int mt = 0; mt < 4; mt++)
            #pragma unroll
            for (int nt = 0; nt < 2; nt++)
                #pragma unroll
                for (int q = 0; q < 4; q++) {
                    int r = mt * 16 + quad * 4 + q;
                    sA[r * KP + ncol0 + nt * 16 + l15] =
                        f2bf(fmaxf(acc[mt][nt][q], 0.f));
                }
        __syncthreads();
    }

    {
        const int col = wave * 16 + l15;
        short8 bw[4];
        #pragma unroll
        for (int kk = 0; kk < 4; kk++) {
            short8 t;
            #pragma unroll
            for (int j = 0; j < 8; j++)
                t[j] = (short)f2bf(wread(Wn2, (size_t)(kk * 32 + quad * 8 + j) * 64 + col, f32));
            bw[kk] = t;
        }
        float bv = wread(bn2, col, f32);
        f32x4 acc[4];
        #pragma unroll
        for (int mt = 0; mt < 4; mt++) {
            acc[mt][0] = bv; acc[mt][1] = bv; acc[mt][2] = bv; acc[mt][3] = bv;
        }
        #pragma unroll
        for (int kk = 0; kk < 4; kk++) {
            short8 a[4];
            #pragma unroll
            for (int mt = 0; mt < 4; mt++)
                a[mt] = *(const short8*)(&sA[(mt * 16 + l15) * KP + kk * 32 + quad * 8]);
            #pragma unroll
            for (int mt = 0; mt < 4; mt++)
                acc[mt] = __builtin_amdgcn_mfma_f32_16x16x32_bf16(
                    a[mt], bw[kk], acc[mt], 0, 0, 0);
        }
        #pragma unroll
        for (int mt = 0; mt < 4; mt++)
            #pragma unroll
            for (int q = 0; q < 4; q++) {
                int row = row0 + mt * 16 + quad * 4 + q;
                if (row < M) out[(size_t)row * 64 + col] = acc[mt][q];
            }
    }
}

// ---------------------------------------------------------------------------
// Edge A/B: A = h@We1_top + be1 -> Axw; B = h@We1_bot -> Bsc (scratch in the
// out-node region, NOT in-place: h stays intact so node_mlp can run last).
// ---------------------------------------------------------------------------
__global__ __launch_bounds__(256) void edge_ab_kernel(
    const unsigned short* __restrict__ h, const void* __restrict__ We1,
    const void* __restrict__ be1, unsigned short* __restrict__ Axw,
    unsigned short* __restrict__ Bsc, int M, const int* __restrict__ f32flag)
{
    constexpr int KP = 128 + 8;
    __shared__ unsigned short sA[64 * KP];
    const int f32 = *f32flag;
    const int tid = threadIdx.x;
    const int row0 = blockIdx.x * 64;

    for (int c = tid; c < 64 * 16; c += 256) {
        int r = c >> 4, cp = c & 15;
        int gr = row0 + r;
        uint4 v = {0u, 0u, 0u, 0u};
        if (gr < M) v = *(const uint4*)(h + (size_t)gr * 128 + cp * 8);
        *(uint4*)(&sA[r * KP + cp * 8]) = v;
    }
    __syncthreads();

    const int wave = tid >> 6, lane = tid & 63;
    const int quad = lane >> 4, l15 = lane & 15;
    const int ncol0 = wave * 32;

    #pragma unroll
    for (int half = 0; half < 2; half++) {
        const size_t b_off = (size_t)half * 128 * 128;
        unsigned short* Cp = half ? Bsc : Axw;

        short8 bw[4][2];
        #pragma unroll
        for (int kk = 0; kk < 4; kk++)
            #pragma unroll
            for (int nt = 0; nt < 2; nt++) {
                int n = ncol0 + nt * 16 + l15;
                short8 t;
                #pragma unroll
                for (int j = 0; j < 8; j++)
                    t[j] = (short)f2bf(wread(We1, b_off + (size_t)(kk * 32 + quad * 8 + j) * 128 + n, f32));
                bw[kk][nt] = t;
            }
        float bv[2];
        #pragma unroll
        for (int nt = 0; nt < 2; nt++)
            bv[nt] = half ? 0.f : wread(be1, ncol0 + nt * 16 + l15, f32);

        f32x4 acc[4][2];
        #pragma unroll
        for (int mt = 0; mt < 4; mt++)
            #pragma unroll
            for (int nt = 0; nt < 2; nt++) {
                acc[mt][nt][0] = bv[nt]; acc[mt][nt][1] = bv[nt];
                acc[mt][nt][2] = bv[nt]; acc[mt][nt][3] = bv[nt];
            }
        #pragma unroll
        for (int kk = 0; kk < 4; kk++) {
            short8 a[4];
            #pragma unroll
            for (int mt = 0; mt < 4; mt++)
                a[mt] = *(const short8*)(&sA[(mt * 16 + l15) * KP + kk * 32 + quad * 8]);
            #pragma unroll
            for (int mt = 0; mt < 4; mt++)
                #pragma unroll
                for (int nt = 0; nt < 2; nt++)
                    acc[mt][nt] = __builtin_amdgcn_mfma_f32_16x16x32_bf16(
                        a[mt], bw[kk][nt], acc[mt][nt], 0, 0, 0);
        }
        #pragma unroll
        for (int mt = 0; mt < 4; mt++)
            #pragma unroll
            for (int nt = 0; nt < 2; nt++)
                #pragma unroll
                for (int q = 0; q < 4; q++) {
                    int row = row0 + mt * 16 + quad * 4 + q;
                    if (row < M)
                        Cp[(size_t)row * 128 + ncol0 + nt * 16 + l15] =
                            f2bf(acc[mt][nt][q]);
                }
    }
}

// ---- CSR build (dst-grouped; for aggregation) ----
__global__ void count_kernel(const int* e32, const int* iflag, int* cnt) {
    int e = blockIdx.x * 256 + threadIdx.x;
    if (e < NEDGES) atomicAdd(&cnt[eget(e32, iflag, 1, e)], 1);
}
__global__ void scan1_kernel(const int* cnt, int* off, int* bsum) {
    __shared__ int s[256];
    int t = threadIdx.x, i = blockIdx.x * 256 + t;
    int v = (i < NNODES) ? cnt[i] : 0;
    s[t] = v;
    __syncthreads();
    for (int d = 1; d < 256; d <<= 1) {
        int add = (t >= d) ? s[t - d] : 0;
        __syncthreads();
        s[t] += add;
        __syncthreads();
    }
    if (i < NNODES) off[i] = s[t] - v;
    if (t == 255) bsum[blockIdx.x] = s[255];
}
__global__ void scan2_kernel(int* bsum, int nblk) {
    if (threadIdx.x == 0 && blockIdx.x == 0) {
        int run = 0;
        for (int c = 0; c < nblk; c++) { int t = bsum[c]; bsum[c] = run; run += t; }
    }
}
__global__ void scan3_kernel(int* off, const int* bsum) {
    int i = blockIdx.x * 256 + threadIdx.x;
    if (i < NNODES) off[i] += bsum[blockIdx.x];
}
__global__ void fill_kernel(const int* e32, const int* iflag, const int* off,
                            int* cur, u64* csrp, int use_pack) {
    int e = blockIdx.x * 256 + threadIdx.x;
    if (e < NEDGES) {
        int s = eget(e32, iflag, 0, e);
        int d = eget(e32, iflag, 1, e);
        int p = atomicAdd(&cur[d], 1);
        int pos = off[d] + p;
        if (use_pack)
            csrp[pos] = (u64)s | ((u64)d << 17) | ((u64)e << 34);
        else
            ((int*)csrp)[pos] = s;
    }
}

// ---- 64-bucket (src-range x dst-range) edge partition for edge_split ----
// bcnt layout: [bucket][chunk] (64 x 3125), bucket-major for direct scan.
__global__ void hist_kernel(const int* e32, const int* iflag, int* bcnt) {
    __shared__ int hcnt[64];
    int tid = threadIdx.x;
    if (tid < 64) hcnt[tid] = 0;
    __syncthreads();
    int e = blockIdx.x * 256 + tid;               // 3125*256 == NEDGES exactly
    int s = eget(e32, iflag, 0, e);
    int d = eget(e32, iflag, 1, e);
    int b = (s / BSLICE) * 8 + (d / BSLICE);
    atomicAdd(&hcnt[b], 1);
    __syncthreads();
    if (tid < 64) bcnt[tid * 3125 + blockIdx.x] = hcnt[tid];
}
// generic in-place exclusive scan (3 stages)
__global__ void gscan1_kernel(int* a, int n, int* bs) {
    __shared__ int s[256];
    int t = threadIdx.x, i = blockIdx.x * 256 + t;
    int v = (i < n) ? a[i] : 0;
    s[t] = v;
    __syncthreads();
    for (int d = 1; d < 256; d <<= 1) {
        int add = (t >= d) ? s[t - d] : 0;
        __syncthreads();
        s[t] += add;
        __syncthreads();
    }
    if (i < n) a[i] = s[t] - v;
    if (t == 255) bs[blockIdx.x] = s[255];
}
__global__ void gscan3_kernel(int* a, int n, const int* bs) {
    int i = blockIdx.x * 256 + threadIdx.x;
    if (i < n) a[i] += bs[blockIdx.x];
}
// scatter into bucketed order (unstable within chunk — outputs routed by eid)
__global__ void scatter_kernel(const int* e32, const int* iflag,
                               const int* bcnt, u64* csrb) {
    __shared__ int curb[64];
    int tid = threadIdx.x;
    if (tid < 64) curb[tid] = 0;
    __syncthreads();
    int e = blockIdx.x * 256 + tid;
    int s = eget(e32, iflag, 0, e);
    int d = eget(e32, iflag, 1, e);
    int b = (s / BSLICE) * 8 + (d / BSLICE);
    int p = atomicAdd(&curb[b], 1);
    int pos = bcnt[b * 3125 + blockIdx.x] + p;
    csrb[pos] = (u64)s | ((u64)d << 17) | ((u64)e << 34);
}

// GAT aggregation (round-11 proven, 2-deep SWP).
__global__ void aggregate_kernel(const unsigned short* __restrict__ xw,
                                 const float* __restrict__ as_, const float* __restrict__ ad_,
                                 const int* __restrict__ off, const u64* __restrict__ csrp,
                                 int use_pack, const void* __restrict__ gat_b, int boff,
                                 unsigned short* __restrict__ h,
                                 const int* __restrict__ f32flag) {
    const int f32 = *f32flag;
    int wave = threadIdx.x >> 6, lane = threadIdx.x & 63;
    int n = blockIdx.x * 4 + wave;
    if (n >= NNODES) return;
    int o0 = off[n];
    int o1 = (n == NNODES - 1) ? NEDGES : off[n + 1];
    int deg = o1 - o0;
    float adn = ad_[n];
    float lself = leaky(as_[n] + adn);

    int deg64 = deg < 64 ? deg : 64;
    int idxv = 0; float av = 0.f;
    if (lane < deg64) {
        idxv = use_pack ? (int)(csrp[o0 + lane] & 0x1FFFF)
                        : ((const int*)csrp)[o0 + lane];
        av = as_[idxv];
    }

    float m = lself;
    if (lane < deg64) m = fmaxf(m, leaky(av + adn));
    for (int i = 64 + lane; i < deg; i += 64) {
        int s = use_pack ? (int)(csrp[o0 + i] & 0x1FFFF)
                         : ((const int*)csrp)[o0 + i];
        m = fmaxf(m, leaky(as_[s] + adn));
    }
    #pragma unroll
    for (int d = 32; d >= 1; d >>= 1) m = fmaxf(m, __shfl_xor(m, d));

    const int slot = lane >> 4;
    const int l15  = lane & 15;
    float denom = 0.f;
    float acc[8];
    #pragma unroll
    for (int k = 0; k < 8; k++) acc[k] = 0.f;

    int i0 = slot, i1 = slot + 4;
    int sidx0 = __shfl(idxv, i0 & 63);
    float aval0 = __shfl(av, i0 & 63);
    int sidx1 = __shfl(idxv, i1 & 63);
    float aval1 = __shfl(av, i1 & 63);
    uint4 rv0 = {0u, 0u, 0u, 0u}, rv1 = {0u, 0u, 0u, 0u};
    if (i0 < deg64) rv0 = *(const uint4*)(xw + (size_t)sidx0 * HDIM + l15 * 8);
    if (i1 < deg64) rv1 = *(const uint4*)(xw + (size_t)sidx1 * HDIM + l15 * 8);
    for (int t0 = 0; t0 < deg64; t0 += 4) {
        int i2 = i0 + 8;
        int sidx2 = __shfl(idxv, i2 & 63);
        float aval2 = __shfl(av, i2 & 63);
        uint4 rv2 = {0u, 0u, 0u, 0u};
        if (i2 < deg64)
            rv2 = *(const uint4*)(xw + (size_t)sidx2 * HDIM + l15 * 8);
        if (i0 < deg64) {
            float p = __expf(leaky(aval0 + adn) - m);
            denom += p;
            const unsigned short* rp = (const unsigned short*)&rv0;
            #pragma unroll
            for (int k = 0; k < 8; k++) acc[k] += p * bf2f(rp[k]);
        }
        i0 = i1; aval0 = aval1; rv0 = rv1;
        i1 = i2; aval1 = aval2; rv1 = rv2;
    }
    for (int i = 64 + slot; i < deg; i += 4) {
        int s = use_pack ? (int)(csrp[o0 + i] & 0x1FFFF)
                         : ((const int*)csrp)[o0 + i];
        float p = __expf(leaky(as_[s] + adn) - m);
        denom += p;
        uint4 rv = *(const uint4*)(xw + (size_t)s * HDIM + l15 * 8);
        const unsigned short* rp = (const unsigned short*)&rv;
        #pragma unroll
        for (int k = 0; k < 8; k++) acc[k] += p * bf2f(rp[k]);
    }

    #pragma unroll
    for (int d = 16; d <= 32; d <<= 1) {
        denom += __shfl_xor(denom, d);
        #pragma unroll
        for (int k = 0; k < 8; k++) acc[k] += __shfl_xor(acc[k], d);
    }

    float ps = __expf(lself - m);
    denom += ps;
    uint4 sv = *(const uint4*)(xw + (size_t)n * HDIM + l15 * 8);
    const unsigned short* sp = (const unsigned short*)&sv;
    #pragma unroll
    for (int k = 0; k < 8; k++) acc[k] += ps * bf2f(sp[k]);

    if (slot == 0) {
        float inv = 1.f / denom;
        size_t base = (size_t)n * HDIM + l15 * 8;
        uint4 hv = *(const uint4*)(h + base);
        const unsigned short* hp = (const unsigned short*)&hv;
        unsigned short outv[8];
        #pragma unroll
        for (int k = 0; k < 8; k++) {
            float hx = bf2f(hp[k]);
            float bx = wread(gat_b, boff + l15 * 8 + k, f32);
            outv[k] = f2bf(fmaxf(hx + acc[k] * inv + bx, 0.f));
        }
        *(uint4*)(h + base) = *(uint4*)outv;
    }
}

// ---------------------------------------------------------------------------
// Edge MLP final, 2D-tiled: XCD k (= blockIdx&7) processes buckets k*8..k*8+7
// (fixed 1.6 MB A-slice resident in that XCD's L2; per-tile 1.6 MB B-slice).
// Round-9 proven 2x-unroll body; per-edge arithmetic identical; outputs
// routed by eid -> bit-identical. use_big=0 fallback: original edge order.
// ---------------------------------------------------------------------------
__global__ __launch_bounds__(256) void edge_split_kernel(
    const unsigned short* __restrict__ A, const unsigned short* __restrict__ B,
    const int* __restrict__ e32, const int* __restrict__ iflag,
    const u64* __restrict__ csrb, const int* __restrict__ bcnt, int use_big,
    const void* __restrict__ We2, const void* __restrict__ be2,
    float* __restrict__ eout, const int* __restrict__ f32flag)
{
    const int f32 = *f32flag;
    const int lane = threadIdx.x & 63;
    const int slot = lane >> 4, l15 = lane & 15;

    float w2[8][3];
    #pragma unroll
    for (int j = 0; j < 8; j++)
        #pragma unroll
        for (int c = 0; c < 3; c++)
            w2[j][c] = wread(We2, (l15 * 8 + j) * 3 + c, f32);
    const float bo0 = wread(be2, 0, f32);
    const float bo1 = wread(be2, 1, f32);
    const float bo2 = wread(be2, 2, f32);

    auto do_pair = [&](int s0, int d0, int oe0,
                       int s1, int d1, int oe1, bool has1) {
        uint4 a0 = *(const uint4*)(A + (size_t)s0 * HDIM + l15 * 8);
        uint4 b0 = *(const uint4*)(B + (size_t)d0 * HDIM + l15 * 8);
        uint4 a1 = {0u, 0u, 0u, 0u}, b1 = {0u, 0u, 0u, 0u};
        if (has1) {
            a1 = *(const uint4*)(A + (size_t)s1 * HDIM + l15 * 8);
            b1 = *(const uint4*)(B + (size_t)d1 * HDIM + l15 * 8);
        }
        const unsigned short* ap0 = (const unsigned short*)&a0;
        const unsigned short* bp0 = (const unsigned short*)&b0;
        const unsigned short* ap1 = (const unsigned short*)&a1;
        const unsigned short* bp1 = (const unsigned short*)&b1;
        float s00 = 0.f, s01 = 0.f, s02 = 0.f;
        float s10 = 0.f, s11 = 0.f, s12 = 0.f;
        #pragma unroll
        for (int j = 0; j < 8; j++) {
            float v0 = fmaxf(bf2f(ap0[j]) + bf2f(bp0[j]), 0.f);
            float v1 = fmaxf(bf2f(ap1[j]) + bf2f(bp1[j]), 0.f);
            s00 += v0 * w2[j][0]; s01 += v0 * w2[j][1]; s02 += v0 * w2[j][2];
            s10 += v1 * w2[j][0]; s11 += v1 * w2[j][1]; s12 += v1 * w2[j][2];
        }
        #pragma unroll
        for (int dd = 1; dd < 16; dd <<= 1) {
            s00 += __shfl_xor(s00, dd); s01 += __shfl_xor(s01, dd); s02 += __shfl_xor(s02, dd);
            s10 += __shfl_xor(s10, dd); s11 += __shfl_xor(s11, dd); s12 += __shfl_xor(s12, dd);
        }
        if (l15 == 0) {
            eout[(size_t)oe0 * 3 + 0] = s00 + bo0;
            eout[(size_t)oe0 * 3 + 1] = s01 + bo1;
            eout[(size_t)oe0 * 3 + 2] = s02 + bo2;
            if (has1) {
                eout[(size_t)oe1 * 3 + 0] = s10 + bo0;
                eout[(size_t)oe1 * 3 + 1] = s11 + bo1;
                eout[(size_t)oe1 * 3 + 2] = s12 + bo2;
            }
        }
    };

    if (use_big) {
        const int kx = blockIdx.x & 7;                 // XCD / src-range
        const int wloc = (blockIdx.x >> 3) * 4 + (threadIdx.x >> 6); // 0..1023
        for (int j = 0; j < 8; j++) {
            int b = kx * 8 + j;
            int base = bcnt[b * 3125];
            int end  = (b == 63) ? NEDGES : bcnt[(b + 1) * 3125];
            for (int e0 = base + wloc * 8 + slot * 2; e0 < end; e0 += 1024 * 8) {
                u64 p0 = csrb[e0];
                int s0 = (int)(p0 & 0x1FFFF);
                int d0 = (int)((p0 >> 17) & 0x1FFFF);
                int o0 = (int)(p0 >> 34);
                bool has1 = (e0 + 1 < end);
                int s1 = 0, d1 = 0, o1 = 0;
                if (has1) {
                    u64 p1 = csrb[e0 + 1];
                    s1 = (int)(p1 & 0x1FFFF);
                    d1 = (int)((p1 >> 17) & 0x1FFFF);
                    o1 = (int)(p1 >> 34);
                }
                do_pair(s0, d0, o0, s1, d1, o1, has1);
            }
        }
    } else {
        const int gw = (blockIdx.x * 256 + threadIdx.x) >> 6;
        const int stride = gridDim.x * 32;
        for (int e0 = gw * 8 + slot * 2; e0 < NEDGES; e0 += stride) {
            int s0 = eget(e32, iflag, 0, e0);
            int d0 = eget(e32, iflag, 1, e0);
            bool has1 = (e0 + 1 < NEDGES);
            int s1 = 0, d1 = 0, o1 = 0;
            if (has1) {
                s1 = eget(e32, iflag, 0, e0 + 1);
                d1 = eget(e32, iflag, 1, e0 + 1);
                o1 = e0 + 1;
            }
            do_pair(s0, d0, e0, s1, d1, o1, has1);
        }
    }
}

__global__ void gout_kernel(const float* gsum, float* out) {
    int f = threadIdx.x;
    out[GEMB_OFF + f] = gsum[f] * (1.f / (float)NNODES);
}

extern "C" __attribute__((visibility("default")))
void kernel_launch(void* const* d_in, const int* in_sizes, int n_in,
                   void* d_out, int out_size, void* d_ws, size_t ws_size,
                   hipStream_t stream) {
    const void* x      = d_in[0];
    const int*  eidx   = (const int*)d_in[1];
    const void* W_emb  = d_in[2];
    const void* b_emb  = d_in[3];
    const void* gat_W  = d_in[4];
    const void* gat_as = d_in[5];
    const void* gat_ad = d_in[6];
    const void* gat_b  = d_in[7];
    const void* Wn1    = d_in[8];
    const void* bn1    = d_in[9];
    const void* Wn2    = d_in[10];
    const void* bn2    = d_in[11];
    const void* We1    = d_in[12];
    const void* be1    = d_in[13];
    const void* We2    = d_in[14];
    const void* be2    = d_in[15];
    float* out = (float*)d_out;   // output dtype: float32

    char* ws = (char*)d_ws;
    unsigned short* h       = (unsigned short*)(ws);                // 12.8 MB
    unsigned short* xw      = (unsigned short*)(ws + 12800000);     // 12.8 MB
    float*          alpha_s = (float*)(ws + 25600000);              // 200 KB
    float*          alpha_d = (float*)(ws + 25800000);              // 200 KB
    int*            cnt     = (int*)(ws + 26000000);                // 200 KB
    int*            off     = (int*)(ws + 26200000);                // 200 KB
    int*            bsum    = (int*)(ws + 26400000);                // 1 KB
    float*          gsum    = (float*)(ws + 26401024);              // 512 B
    int*            iflag   = (int*)(ws + 26401536);
    int*            fflag   = (int*)(ws + 26401540);
    u64*            csrp    = (u64*)(ws + 26608000);                // 6.4 MB (dst-grouped)
    int*            cur     = (int*)alpha_s;                        // dead until layer loop
    // After the layer loop: alpha/cnt/off and csrp are dead ->
    int*            bcnt    = (int*)(ws + 25600000);                // 800,000 B (64x3125)
    u64*            csrb    = (u64*)(ws + 29808000);                // 6.4 MB -> 36.208 MB
    int*            bsum2   = (int*)(ws + 29808000);                // 782 ints, pre-scatter only
    // B scratch for the edge MLP lives in the out node region (overwritten by
    // node_mlp afterwards):
    unsigned short* Bsc     = (unsigned short*)out;                 // 12.8 MB

    const int use_pack = (ws_size >= (size_t)33008000) ? 1 : 0;
    const int use_big  = (ws_size >= (size_t)36208000) ? 1 : 0;    // proven in round 2

    const int node_blks = (NNODES + 255) / 256;    // 196
    const int edge_blks = (NEDGES + 255) / 256;    // 3125
    const int g64       = (NNODES + 63) / 64;      // 782

    init_kernel<<<node_blks, 256, 0, stream>>>(cnt, cur, gsum, iflag);
    detect_kernel<<<2, 256, 0, stream>>>((const unsigned short*)x, eidx, fflag, iflag);

    // embedding: h = relu(x @ W_emb + b_emb)
    gemm_mfma_kernel<<<g64, 256, 0, stream>>>(
        x, 1, W_emb, 0, b_emb, h, NNODES, 1, fflag,
        (float*)0, (float*)0, (const void*)0, (const void*)0, 0);

    // dst-grouped CSR (for aggregation)
    count_kernel<<<edge_blks, 256, 0, stream>>>(eidx, iflag, cnt);
    scan1_kernel<<<node_blks, 256, 0, stream>>>(cnt, off, bsum);
    scan2_kernel<<<1, 64, 0, stream>>>(bsum, node_blks);
    scan3_kernel<<<node_blks, 256, 0, stream>>>(off, bsum);
    fill_kernel<<<edge_blks, 256, 0, stream>>>(eidx, iflag, off, cur, csrp, use_pack);

    for (int l = 0; l < NLAYERS; l++) {
        gemm_mfma_kernel<<<g64, 256, 0, stream>>>(
            h, 0, gat_W, (size_t)l * HDIM * HDIM, (const void*)0, xw, NNODES, 0, fflag,
            alpha_s, alpha_d, gat_as, gat_ad, l * HDIM);
        aggregate_kernel<<<(NNODES + 3) / 4, 256, 0, stream>>>(
            xw, alpha_s, alpha_d, off, csrp, use_pack, gat_b, l * HDIM, h, fflag);
    }

    // 64-bucket edge partition (alpha/cnt/off + csrp now dead)
    if (use_big) {
        hist_kernel<<<3125, 256, 0, stream>>>(eidx, iflag, bcnt);
        gscan1_kernel<<<782, 256, 0, stream>>>(bcnt, 200000, bsum2);
        scan2_kernel<<<1, 64, 0, stream>>>(bsum2, 782);
        gscan3_kernel<<<782, 256, 0, stream>>>(bcnt, 200000, bsum2);
        scatter_kernel<<<3125, 256, 0, stream>>>(eidx, iflag, bcnt, csrb);
    }

    // edge pipeline: A -> xw, B -> out-node scratch (h untouched)
    edge_ab_kernel<<<g64, 256, 0, stream>>>(
        h, We1, be1, xw, Bsc, NNODES, fflag);
    edge_split_kernel<<<2048, 256, 0, stream>>>(
        xw, Bsc, eidx, iflag, csrb, bcnt, use_big, We2, be2,
        out + NODE_OUT_ELEMS, fflag);

    // node MLP last (h intact; overwrites the B scratch region) + gsum
    node_mlp_kernel<<<g64, 256, 0, stream>>>(
        h, Wn1, bn1, Wn2, bn2, out, gsum, NNODES, fflag);
    gout_kernel<<<1, 128, 0, stream>>>(gsum, out);
}

// Round 15
// 549.792 us; speedup vs baseline: 1.1910x; 1.1910x over previous
//
#include <hip/hip_runtime.h>

#define NNODES 50000
#define NEDGES 800000
#define HDIM 128
#define DOUT 64
#define NLAYERS 3
#define NEG_SLOPE 0.2f
#define BSLICE 6250                                // node-range per bucket dim

#define NODE_OUT_ELEMS (NNODES * DOUT)             // 3,200,000
#define EDGE_OUT_ELEMS (NEDGES * 3)                // 2,400,000
#define GEMB_OFF (NODE_OUT_ELEMS + EDGE_OUT_ELEMS) // 5,600,000

typedef __attribute__((ext_vector_type(8))) short short8;
typedef __attribute__((ext_vector_type(4))) float f32x4;
typedef unsigned long long u64;

__device__ __forceinline__ float bf2f(unsigned short u) {
    union { unsigned int i; float f; } v; v.i = ((unsigned int)u) << 16; return v.f;
}
__device__ __forceinline__ unsigned short f2bf(float f) {
    union { unsigned int i; float f; } v; v.f = f;
    unsigned int b = v.i;
    unsigned int r = (b + 0x7FFFu + ((b >> 16) & 1u)) >> 16;
    return (unsigned short)r;
}
__device__ __forceinline__ float leaky(float x) { return x > 0.f ? x : NEG_SLOPE * x; }
__device__ __forceinline__ float wread(const void* p, size_t i, int f32) {
    return f32 ? ((const float*)p)[i] : bf2f(((const unsigned short*)p)[i]);
}
__device__ __forceinline__ int eget(const int* e32, const int* iflag, int which, int e) {
    int idx = which * NEDGES + e;
    return (*iflag) ? e32[idx] : e32[2 * idx];
}

// Zero cnt, cur, gsum, flags in one launch.
__global__ void init_kernel(int* cnt, int* cur, float* gsum, int* flags) {
    int i = blockIdx.x * 256 + threadIdx.x;
    if (i < NNODES) { cnt[i] = 0; cur[i] = 0; }
    if (blockIdx.x == 0) {
        if (threadIdx.x < HDIM) gsum[threadIdx.x] = 0.f;
        if (threadIdx.x < 2) flags[threadIdx.x] = 0;
    }
}

// block 0: sampled f32 detect on x; block 1: sampled i64 detect on edges.
__global__ void detect_kernel(const unsigned short* xb, const int* e32,
                              int* fflag, int* iflag) {
    if (blockIdx.x == 0) {
        int hit = 0;
        for (int j = threadIdx.x; j < 4096; j += 256) {
            int e = (xb[j] >> 7) & 0xFF;
            if (e >= 0x90) hit = 1;
        }
        if (hit) atomicOr(fflag, 1);
    } else {
        int hit = 0;
        for (int t = threadIdx.x; t < 16384; t += 256) {
            int i = t * 48;
            if (e32[2 * i + 1] != 0) hit = 1;
        }
        if (__any(hit)) {
            if ((threadIdx.x & 63) == 0) atomicOr(iflag, 1);
        }
    }
}

// Parallel single-block exclusive scan, n <= 1024 (replaces the serial
// scan2_kernel that cost 85 us at n=782 — round-14 top dispatch).
__global__ void bscan_kernel(int* a, int n) {
    __shared__ int s[1024];
    int t = threadIdx.x;
    int v = (t < n) ? a[t] : 0;
    s[t] = v;
    __syncthreads();
    for (int d = 1; d < 1024; d <<= 1) {
        int add = (t >= d) ? s[t - d] : 0;
        __syncthreads();
        s[t] += add;
        __syncthreads();
    }
    if (t < n) a[t] = s[t] - v;   // exclusive
}

// ---------------------------------------------------------------------------
// MFMA GEMM, N=128 (+ fused alpha for layer GEMMs). Round-11 proven.
// ---------------------------------------------------------------------------
__global__ __launch_bounds__(256) void gemm_mfma_kernel(
    const void* __restrict__ Av, int a_from_x, const void* __restrict__ Bw,
    size_t b_off, const void* __restrict__ bias, unsigned short* __restrict__ C,
    int M, int relu, const int* __restrict__ f32flag,
    float* __restrict__ alpha_s, float* __restrict__ alpha_d,
    const void* __restrict__ gat_as, const void* __restrict__ gat_ad, int aoff)
{
    constexpr int KP = 128 + 8;
    __shared__ unsigned short sA[64 * KP];
    __shared__ float pS[64][4], pD[64][4];
    const int f32 = *f32flag;
    const int tid = threadIdx.x;
    const int row0 = blockIdx.x * 64;

    if (a_from_x && f32) {
        const float* Af = (const float*)Av;
        for (int c = tid; c < 64 * 16; c += 256) {
            int r = c >> 4, cp = c & 15;
            int gr = row0 + r;
            unsigned short o[8] = {0, 0, 0, 0, 0, 0, 0, 0};
            if (gr < M) {
                float4 v0 = *(const float4*)(Af + (size_t)gr * 128 + cp * 8);
                float4 v1 = *(const float4*)(Af + (size_t)gr * 128 + cp * 8 + 4);
                o[0] = f2bf(v0.x); o[1] = f2bf(v0.y); o[2] = f2bf(v0.z); o[3] = f2bf(v0.w);
                o[4] = f2bf(v1.x); o[5] = f2bf(v1.y); o[6] = f2bf(v1.z); o[7] = f2bf(v1.w);
            }
            *(uint4*)(&sA[r * KP + cp * 8]) = *(uint4*)o;
        }
    } else {
        const unsigned short* A = (const unsigned short*)Av;
        for (int c = tid; c < 64 * 16; c += 256) {
            int r = c >> 4, cp = c & 15;
            int gr = row0 + r;
            uint4 v = {0u, 0u, 0u, 0u};
            if (gr < M) v = *(const uint4*)(A + (size_t)gr * 128 + cp * 8);
            *(uint4*)(&sA[r * KP + cp * 8]) = v;
        }
    }
    __syncthreads();

    const int wave = tid >> 6, lane = tid & 63;
    const int quad = lane >> 4, l15 = lane & 15;
    const int ncol0 = wave * 32;

    short8 bw[4][2];
    #pragma unroll
    for (int kk = 0; kk < 4; kk++)
        #pragma unroll
        for (int nt = 0; nt < 2; nt++) {
            int n = ncol0 + nt * 16 + l15;
            short8 t;
            #pragma unroll
            for (int j = 0; j < 8; j++)
                t[j] = (short)f2bf(wread(Bw, b_off + (size_t)(kk * 32 + quad * 8 + j) * 128 + n, f32));
            bw[kk][nt] = t;
        }

    float bv[2];
    #pragma unroll
    for (int nt = 0; nt < 2; nt++)
        bv[nt] = bias ? wread(bias, ncol0 + nt * 16 + l15, f32) : 0.f;

    f32x4 acc[4][2];
    #pragma unroll
    for (int mt = 0; mt < 4; mt++)
        #pragma unroll
        for (int nt = 0; nt < 2; nt++) {
            acc[mt][nt][0] = bv[nt]; acc[mt][nt][1] = bv[nt];
            acc[mt][nt][2] = bv[nt]; acc[mt][nt][3] = bv[nt];
        }

    #pragma unroll
    for (int kk = 0; kk < 4; kk++) {
        short8 a[4];
        #pragma unroll
        for (int mt = 0; mt < 4; mt++)
            a[mt] = *(const short8*)(&sA[(mt * 16 + l15) * KP + kk * 32 + quad * 8]);
        #pragma unroll
        for (int mt = 0; mt < 4; mt++)
            #pragma unroll
            for (int nt = 0; nt < 2; nt++)
                acc[mt][nt] = __builtin_amdgcn_mfma_f32_16x16x32_bf16(
                    a[mt], bw[kk][nt], acc[mt][nt], 0, 0, 0);
    }

    if (alpha_s) {
        float as0 = wread(gat_as, (size_t)aoff + ncol0 + l15, f32);
        float as1 = wread(gat_as, (size_t)aoff + ncol0 + 16 + l15, f32);
        float ad0 = wread(gat_ad, (size_t)aoff + ncol0 + l15, f32);
        float ad1 = wread(gat_ad, (size_t)aoff + ncol0 + 16 + l15, f32);
        #pragma unroll
        for (int mt = 0; mt < 4; mt++)
            #pragma unroll
            for (int q = 0; q < 4; q++) {
                float vs = acc[mt][0][q] * as0 + acc[mt][1][q] * as1;
                float vd = acc[mt][0][q] * ad0 + acc[mt][1][q] * ad1;
                #pragma unroll
                for (int d = 1; d < 16; d <<= 1) {
                    vs += __shfl_xor(vs, d);
                    vd += __shfl_xor(vd, d);
                }
                if (l15 == 0) {
                    int r = mt * 16 + quad * 4 + q;
                    pS[r][wave] = vs; pD[r][wave] = vd;
                }
            }
        __syncthreads();
        if (tid < 64) {
            int row = row0 + tid;
            if (row < M) {
                alpha_s[row] = pS[tid][0] + pS[tid][1] + pS[tid][2] + pS[tid][3];
                alpha_d[row] = pD[tid][0] + pD[tid][1] + pD[tid][2] + pD[tid][3];
            }
        }
    }

    #pragma unroll
    for (int mt = 0; mt < 4; mt++)
        #pragma unroll
        for (int nt = 0; nt < 2; nt++)
            #pragma unroll
            for (int q = 0; q < 4; q++) {
                int row = row0 + mt * 16 + quad * 4 + q;
                if (row < M) {
                    float v = acc[mt][nt][q];
                    if (relu) v = fmaxf(v, 0.f);
                    C[(size_t)row * 128 + ncol0 + nt * 16 + l15] = f2bf(v);
                }
            }
}

// ---------------------------------------------------------------------------
// Fused node MLP (+ gsum). Round-11 proven. Runs LAST (h intact).
// ---------------------------------------------------------------------------
__global__ __launch_bounds__(256) void node_mlp_kernel(
    const unsigned short* __restrict__ h, const void* __restrict__ Wn1,
    const void* __restrict__ bn1, const void* __restrict__ Wn2,
    const void* __restrict__ bn2, float* __restrict__ out,
    float* __restrict__ gsum, int M, const int* __restrict__ f32flag)
{
    constexpr int KP = 128 + 8;
    __shared__ unsigned short sA[64 * KP];
    const int f32 = *f32flag;
    const int tid = threadIdx.x;
    const int row0 = blockIdx.x * 64;

    for (int c = tid; c < 64 * 16; c += 256) {
        int r = c >> 4, cp = c & 15;
        int gr = row0 + r;
        uint4 v = {0u, 0u, 0u, 0u};
        if (gr < M) v = *(const uint4*)(h + (size_t)gr * 128 + cp * 8);
        *(uint4*)(&sA[r * KP + cp * 8]) = v;
    }
    __syncthreads();

    if (tid < 128) {
        float hs = 0.f;
        for (int r = 0; r < 64; r++) hs += bf2f(sA[r * KP + tid]);
        atomicAdd(&gsum[tid], hs);
    }

    const int wave = tid >> 6, lane = tid & 63;
    const int quad = lane >> 4, l15 = lane & 15;
    const int ncol0 = wave * 32;

    {
        short8 bw[4][2];
        #pragma unroll
        for (int kk = 0; kk < 4; kk++)
            #pragma unroll
            for (int nt = 0; nt < 2; nt++) {
                int n = ncol0 + nt * 16 + l15;
                short8 t;
                #pragma unroll
                for (int j = 0; j < 8; j++)
                    t[j] = (short)f2bf(wread(Wn1, (size_t)(kk * 32 + quad * 8 + j) * 128 + n, f32));
                bw[kk][nt] = t;
            }
        float bv[2];
        #pragma unroll
        for (int nt = 0; nt < 2; nt++)
            bv[nt] = wread(bn1, ncol0 + nt * 16 + l15, f32);

        f32x4 acc[4][2];
        #pragma unroll
        for (int mt = 0; mt < 4; mt++)
            #pragma unroll
            for (int nt = 0; nt < 2; nt++) {
                acc[mt][nt][0] = bv[nt]; acc[mt][nt][1] = bv[nt];
                acc[mt][nt][2] = bv[nt]; acc[mt][nt][3] = bv[nt];
            }
        #pragma unroll
        for (int kk = 0; kk < 4; kk++) {
            short8 a[4];
            #pragma unroll
            for (int mt = 0; mt < 4; mt++)
                a[mt] = *(const short8*)(&sA[(mt * 16 + l15) * KP + kk * 32 + quad * 8]);
            #pragma unroll
            for (int mt = 0; mt < 4; mt++)
                #pragma unroll
                for (int nt = 0; nt < 2; nt++)
                    acc[mt][nt] = __builtin_amdgcn_mfma_f32_16x16x32_bf16(
                        a[mt], bw[kk][nt], acc[mt][nt], 0, 0, 0);
        }
        __syncthreads();
        #pragma unroll
        for (int mt = 0; mt < 4; mt++)
            #pragma unroll
            for (int nt = 0; nt < 2; nt++)
                #pragma unroll
                for (int q = 0; q < 4; q++) {
                    int r = mt * 16 + quad * 4 + q;
                    sA[r * KP + ncol0 + nt * 16 + l15] =
                        f2bf(fmaxf(acc[mt][nt][q], 0.f));
                }
        __syncthreads();
    }

    {
        const int col = wave * 16 + l15;
        short8 bw[4];
        #pragma unroll
        for (int kk = 0; kk < 4; kk++) {
            short8 t;
            #pragma unroll
            for (int j = 0; j < 8; j++)
                t[j] = (short)f2bf(wread(Wn2, (size_t)(kk * 32 + quad * 8 + j) * 64 + col, f32));
            bw[kk] = t;
        }
        float bv = wread(bn2, col, f32);
        f32x4 acc[4];
        #pragma unroll
        for (int mt = 0; mt < 4; mt++) {
            acc[mt][0] = bv; acc[mt][1] = bv; acc[mt][2] = bv; acc[mt][3] = bv;
        }
        #pragma unroll
        for (int kk = 0; kk < 4; kk++) {
            short8 a[4];
            #pragma unroll
            for (int mt = 0; mt < 4; mt++)
                a[mt] = *(const short8*)(&sA[(mt * 16 + l15) * KP + kk * 32 + quad * 8]);
            #pragma unroll
            for (int mt = 0; mt < 4; mt++)
                acc[mt] = __builtin_amdgcn_mfma_f32_16x16x32_bf16(
                    a[mt], bw[kk], acc[mt], 0, 0, 0);
        }
        #pragma unroll
        for (int mt = 0; mt < 4; mt++)
            #pragma unroll
            for (int q = 0; q < 4; q++) {
                int row = row0 + mt * 16 + quad * 4 + q;
                if (row < M) out[(size_t)row * 64 + col] = acc[mt][q];
            }
    }
}

// ---------------------------------------------------------------------------
// Edge A/B: A = h@We1_top + be1 -> Axw; B = h@We1_bot -> Bsc (out-region
// scratch; h stays intact so node_mlp can run last).
// ---------------------------------------------------------------------------
__global__ __launch_bounds__(256) void edge_ab_kernel(
    const unsigned short* __restrict__ h, const void* __restrict__ We1,
    const void* __restrict__ be1, unsigned short* __restrict__ Axw,
    unsigned short* __restrict__ Bsc, int M, const int* __restrict__ f32flag)
{
    constexpr int KP = 128 + 8;
    __shared__ unsigned short sA[64 * KP];
    const int f32 = *f32flag;
    const int tid = threadIdx.x;
    const int row0 = blockIdx.x * 64;

    for (int c = tid; c < 64 * 16; c += 256) {
        int r = c >> 4, cp = c & 15;
        int gr = row0 + r;
        uint4 v = {0u, 0u, 0u, 0u};
        if (gr < M) v = *(const uint4*)(h + (size_t)gr * 128 + cp * 8);
        *(uint4*)(&sA[r * KP + cp * 8]) = v;
    }
    __syncthreads();

    const int wave = tid >> 6, lane = tid & 63;
    const int quad = lane >> 4, l15 = lane & 15;
    const int ncol0 = wave * 32;

    #pragma unroll
    for (int half = 0; half < 2; half++) {
        const size_t b_off = (size_t)half * 128 * 128;
        unsigned short* Cp = half ? Bsc : Axw;

        short8 bw[4][2];
        #pragma unroll
        for (int kk = 0; kk < 4; kk++)
            #pragma unroll
            for (int nt = 0; nt < 2; nt++) {
                int n = ncol0 + nt * 16 + l15;
                short8 t;
                #pragma unroll
                for (int j = 0; j < 8; j++)
                    t[j] = (short)f2bf(wread(We1, b_off + (size_t)(kk * 32 + quad * 8 + j) * 128 + n, f32));
                bw[kk][nt] = t;
            }
        float bv[2];
        #pragma unroll
        for (int nt = 0; nt < 2; nt++)
            bv[nt] = half ? 0.f : wread(be1, ncol0 + nt * 16 + l15, f32);

        f32x4 acc[4][2];
        #pragma unroll
        for (int mt = 0; mt < 4; mt++)
            #pragma unroll
            for (int nt = 0; nt < 2; nt++) {
                acc[mt][nt][0] = bv[nt]; acc[mt][nt][1] = bv[nt];
                acc[mt][nt][2] = bv[nt]; acc[mt][nt][3] = bv[nt];
            }
        #pragma unroll
        for (int kk = 0; kk < 4; kk++) {
            short8 a[4];
            #pragma unroll
            for (int mt = 0; mt < 4; mt++)
                a[mt] = *(const short8*)(&sA[(mt * 16 + l15) * KP + kk * 32 + quad * 8]);
            #pragma unroll
            for (int mt = 0; mt < 4; mt++)
                #pragma unroll
                for (int nt = 0; nt < 2; nt++)
                    acc[mt][nt] = __builtin_amdgcn_mfma_f32_16x16x32_bf16(
                        a[mt], bw[kk][nt], acc[mt][nt], 0, 0, 0);
        }
        #pragma unroll
        for (int mt = 0; mt < 4; mt++)
            #pragma unroll
            for (int nt = 0; nt < 2; nt++)
                #pragma unroll
                for (int q = 0; q < 4; q++) {
                    int row = row0 + mt * 16 + quad * 4 + q;
                    if (row < M)
                        Cp[(size_t)row * 128 + ncol0 + nt * 16 + l15] =
                            f2bf(acc[mt][nt][q]);
                }
    }
}

// ---- CSR build (dst-grouped; for aggregation) ----
__global__ void count_kernel(const int* e32, const int* iflag, int* cnt) {
    int e = blockIdx.x * 256 + threadIdx.x;
    if (e < NEDGES) atomicAdd(&cnt[eget(e32, iflag, 1, e)], 1);
}
__global__ void scan1_kernel(const int* cnt, int* off, int* bsum) {
    __shared__ int s[256];
    int t = threadIdx.x, i = blockIdx.x * 256 + t;
    int v = (i < NNODES) ? cnt[i] : 0;
    s[t] = v;
    __syncthreads();
    for (int d = 1; d < 256; d <<= 1) {
        int add = (t >= d) ? s[t - d] : 0;
        __syncthreads();
        s[t] += add;
        __syncthreads();
    }
    if (i < NNODES) off[i] = s[t] - v;
    if (t == 255) bsum[blockIdx.x] = s[255];
}
__global__ void scan3_kernel(int* off, const int* bsum) {
    int i = blockIdx.x * 256 + threadIdx.x;
    if (i < NNODES) off[i] += bsum[blockIdx.x];
}
__global__ void fill_kernel(const int* e32, const int* iflag, const int* off,
                            int* cur, u64* csrp, int use_pack) {
    int e = blockIdx.x * 256 + threadIdx.x;
    if (e < NEDGES) {
        int s = eget(e32, iflag, 0, e);
        int d = eget(e32, iflag, 1, e);
        int p = atomicAdd(&cur[d], 1);
        int pos = off[d] + p;
        if (use_pack)
            csrp[pos] = (u64)s | ((u64)d << 17) | ((u64)e << 34);
        else
            ((int*)csrp)[pos] = s;
    }
}

// ---- 64-bucket (src-range x dst-range) edge partition for edge_split ----
__global__ void hist_kernel(const int* e32, const int* iflag, int* bcnt) {
    __shared__ int hcnt[64];
    int tid = threadIdx.x;
    if (tid < 64) hcnt[tid] = 0;
    __syncthreads();
    int e = blockIdx.x * 256 + tid;               // 3125*256 == NEDGES exactly
    int s = eget(e32, iflag, 0, e);
    int d = eget(e32, iflag, 1, e);
    int b = (s / BSLICE) * 8 + (d / BSLICE);
    atomicAdd(&hcnt[b], 1);
    __syncthreads();
    if (tid < 64) bcnt[tid * 3125 + blockIdx.x] = hcnt[tid];
}
__global__ void gscan1_kernel(int* a, int n, int* bs) {
    __shared__ int s[256];
    int t = threadIdx.x, i = blockIdx.x * 256 + t;
    int v = (i < n) ? a[i] : 0;
    s[t] = v;
    __syncthreads();
    for (int d = 1; d < 256; d <<= 1) {
        int add = (t >= d) ? s[t - d] : 0;
        __syncthreads();
        s[t] += add;
        __syncthreads();
    }
    if (i < n) a[i] = s[t] - v;
    if (t == 255) bs[blockIdx.x] = s[255];
}
__global__ void gscan3_kernel(int* a, int n, const int* bs) {
    int i = blockIdx.x * 256 + threadIdx.x;
    if (i < n) a[i] += bs[blockIdx.x];
}
__global__ void scatter_kernel(const int* e32, const int* iflag,
                               const int* bcnt, u64* csrb) {
    __shared__ int curb[64];
    int tid = threadIdx.x;
    if (tid < 64) curb[tid] = 0;
    __syncthreads();
    int e = blockIdx.x * 256 + tid;
    int s = eget(e32, iflag, 0, e);
    int d = eget(e32, iflag, 1, e);
    int b = (s / BSLICE) * 8 + (d / BSLICE);
    int p = atomicAdd(&curb[b], 1);
    int pos = bcnt[b * 3125 + blockIdx.x] + p;
    csrb[pos] = (u64)s | ((u64)d << 17) | ((u64)e << 34);
}

// GAT aggregation (round-11 proven, 2-deep SWP).
__global__ void aggregate_kernel(const unsigned short* __restrict__ xw,
                                 const float* __restrict__ as_, const float* __restrict__ ad_,
                                 const int* __restrict__ off, const u64* __restrict__ csrp,
                                 int use_pack, const void* __restrict__ gat_b, int boff,
                                 unsigned short* __restrict__ h,
                                 const int* __restrict__ f32flag) {
    const int f32 = *f32flag;
    int wave = threadIdx.x >> 6, lane = threadIdx.x & 63;
    int n = blockIdx.x * 4 + wave;
    if (n >= NNODES) return;
    int o0 = off[n];
    int o1 = (n == NNODES - 1) ? NEDGES : off[n + 1];
    int deg = o1 - o0;
    float adn = ad_[n];
    float lself = leaky(as_[n] + adn);

    int deg64 = deg < 64 ? deg : 64;
    int idxv = 0; float av = 0.f;
    if (lane < deg64) {
        idxv = use_pack ? (int)(csrp[o0 + lane] & 0x1FFFF)
                        : ((const int*)csrp)[o0 + lane];
        av = as_[idxv];
    }

    float m = lself;
    if (lane < deg64) m = fmaxf(m, leaky(av + adn));
    for (int i = 64 + lane; i < deg; i += 64) {
        int s = use_pack ? (int)(csrp[o0 + i] & 0x1FFFF)
                         : ((const int*)csrp)[o0 + i];
        m = fmaxf(m, leaky(as_[s] + adn));
    }
    #pragma unroll
    for (int d = 32; d >= 1; d >>= 1) m = fmaxf(m, __shfl_xor(m, d));

    const int slot = lane >> 4;
    const int l15  = lane & 15;
    float denom = 0.f;
    float acc[8];
    #pragma unroll
    for (int k = 0; k < 8; k++) acc[k] = 0.f;

    int i0 = slot, i1 = slot + 4;
    int sidx0 = __shfl(idxv, i0 & 63);
    float aval0 = __shfl(av, i0 & 63);
    int sidx1 = __shfl(idxv, i1 & 63);
    float aval1 = __shfl(av, i1 & 63);
    uint4 rv0 = {0u, 0u, 0u, 0u}, rv1 = {0u, 0u, 0u, 0u};
    if (i0 < deg64) rv0 = *(const uint4*)(xw + (size_t)sidx0 * HDIM + l15 * 8);
    if (i1 < deg64) rv1 = *(const uint4*)(xw + (size_t)sidx1 * HDIM + l15 * 8);
    for (int t0 = 0; t0 < deg64; t0 += 4) {
        int i2 = i0 + 8;
        int sidx2 = __shfl(idxv, i2 & 63);
        float aval2 = __shfl(av, i2 & 63);
        uint4 rv2 = {0u, 0u, 0u, 0u};
        if (i2 < deg64)
            rv2 = *(const uint4*)(xw + (size_t)sidx2 * HDIM + l15 * 8);
        if (i0 < deg64) {
            float p = __expf(leaky(aval0 + adn) - m);
            denom += p;
            const unsigned short* rp = (const unsigned short*)&rv0;
            #pragma unroll
            for (int k = 0; k < 8; k++) acc[k] += p * bf2f(rp[k]);
        }
        i0 = i1; aval0 = aval1; rv0 = rv1;
        i1 = i2; aval1 = aval2; rv1 = rv2;
    }
    for (int i = 64 + slot; i < deg; i += 4) {
        int s = use_pack ? (int)(csrp[o0 + i] & 0x1FFFF)
                         : ((const int*)csrp)[o0 + i];
        float p = __expf(leaky(as_[s] + adn) - m);
        denom += p;
        uint4 rv = *(const uint4*)(xw + (size_t)s * HDIM + l15 * 8);
        const unsigned short* rp = (const unsigned short*)&rv;
        #pragma unroll
        for (int k = 0; k < 8; k++) acc[k] += p * bf2f(rp[k]);
    }

    #pragma unroll
    for (int d = 16; d <= 32; d <<= 1) {
        denom += __shfl_xor(denom, d);
        #pragma unroll
        for (int k = 0; k < 8; k++) acc[k] += __shfl_xor(acc[k], d);
    }

    float ps = __expf(lself - m);
    denom += ps;
    uint4 sv = *(const uint4*)(xw + (size_t)n * HDIM + l15 * 8);
    const unsigned short* sp = (const unsigned short*)&sv;
    #pragma unroll
    for (int k = 0; k < 8; k++) acc[k] += ps * bf2f(sp[k]);

    if (slot == 0) {
        float inv = 1.f / denom;
        size_t base = (size_t)n * HDIM + l15 * 8;
        uint4 hv = *(const uint4*)(h + base);
        const unsigned short* hp = (const unsigned short*)&hv;
        unsigned short outv[8];
        #pragma unroll
        for (int k = 0; k < 8; k++) {
            float hx = bf2f(hp[k]);
            float bx = wread(gat_b, boff + l15 * 8 + k, f32);
            outv[k] = f2bf(fmaxf(hx + acc[k] * inv + bx, 0.f));
        }
        *(uint4*)(h + base) = *(uint4*)outv;
    }
}

// ---------------------------------------------------------------------------
// Edge MLP final, 2D-tiled: XCD k (= blockIdx&7) processes buckets k*8..k*8+7.
// Round-9 proven 2x-unroll body; outputs routed by eid -> bit-identical.
// ---------------------------------------------------------------------------
__global__ __launch_bounds__(256) void edge_split_kernel(
    const unsigned short* __restrict__ A, const unsigned short* __restrict__ B,
    const int* __restrict__ e32, const int* __restrict__ iflag,
    const u64* __restrict__ csrb, const int* __restrict__ bcnt, int use_big,
    const void* __restrict__ We2, const void* __restrict__ be2,
    float* __restrict__ eout, const int* __restrict__ f32flag)
{
    const int f32 = *f32flag;
    const int lane = threadIdx.x & 63;
    const int slot = lane >> 4, l15 = lane & 15;

    float w2[8][3];
    #pragma unroll
    for (int j = 0; j < 8; j++)
        #pragma unroll
        for (int c = 0; c < 3; c++)
            w2[j][c] = wread(We2, (l15 * 8 + j) * 3 + c, f32);
    const float bo0 = wread(be2, 0, f32);
    const float bo1 = wread(be2, 1, f32);
    const float bo2 = wread(be2, 2, f32);

    auto do_pair = [&](int s0, int d0, int oe0,
                       int s1, int d1, int oe1, bool has1) {
        uint4 a0 = *(const uint4*)(A + (size_t)s0 * HDIM + l15 * 8);
        uint4 b0 = *(const uint4*)(B + (size_t)d0 * HDIM + l15 * 8);
        uint4 a1 = {0u, 0u, 0u, 0u}, b1 = {0u, 0u, 0u, 0u};
        if (has1) {
            a1 = *(const uint4*)(A + (size_t)s1 * HDIM + l15 * 8);
            b1 = *(const uint4*)(B + (size_t)d1 * HDIM + l15 * 8);
        }
        const unsigned short* ap0 = (const unsigned short*)&a0;
        const unsigned short* bp0 = (const unsigned short*)&b0;
        const unsigned short* ap1 = (const unsigned short*)&a1;
        const unsigned short* bp1 = (const unsigned short*)&b1;
        float s00 = 0.f, s01 = 0.f, s02 = 0.f;
        float s10 = 0.f, s11 = 0.f, s12 = 0.f;
        #pragma unroll
        for (int j = 0; j < 8; j++) {
            float v0 = fmaxf(bf2f(ap0[j]) + bf2f(bp0[j]), 0.f);
            float v1 = fmaxf(bf2f(ap1[j]) + bf2f(bp1[j]), 0.f);
            s00 += v0 * w2[j][0]; s01 += v0 * w2[j][1]; s02 += v0 * w2[j][2];
            s10 += v1 * w2[j][0]; s11 += v1 * w2[j][1]; s12 += v1 * w2[j][2];
        }
        #pragma unroll
        for (int dd = 1; dd < 16; dd <<= 1) {
            s00 += __shfl_xor(s00, dd); s01 += __shfl_xor(s01, dd); s02 += __shfl_xor(s02, dd);
            s10 += __shfl_xor(s10, dd); s11 += __shfl_xor(s11, dd); s12 += __shfl_xor(s12, dd);
        }
        if (l15 == 0) {
            eout[(size_t)oe0 * 3 + 0] = s00 + bo0;
            eout[(size_t)oe0 * 3 + 1] = s01 + bo1;
            eout[(size_t)oe0 * 3 + 2] = s02 + bo2;
            if (has1) {
                eout[(size_t)oe1 * 3 + 0] = s10 + bo0;
                eout[(size_t)oe1 * 3 + 1] = s11 + bo1;
                eout[(size_t)oe1 * 3 + 2] = s12 + bo2;
            }
        }
    };

    if (use_big) {
        const int kx = blockIdx.x & 7;
        const int wloc = (blockIdx.x >> 3) * 4 + (threadIdx.x >> 6); // 0..1023
        for (int j = 0; j < 8; j++) {
            int b = kx * 8 + j;
            int base = bcnt[b * 3125];
            int end  = (b == 63) ? NEDGES : bcnt[(b + 1) * 3125];
            for (int e0 = base + wloc * 8 + slot * 2; e0 < end; e0 += 1024 * 8) {
                u64 p0 = csrb[e0];
                int s0 = (int)(p0 & 0x1FFFF);
                int d0 = (int)((p0 >> 17) & 0x1FFFF);
                int o0 = (int)(p0 >> 34);
                bool has1 = (e0 + 1 < end);
                int s1 = 0, d1 = 0, o1 = 0;
                if (has1) {
                    u64 p1 = csrb[e0 + 1];
                    s1 = (int)(p1 & 0x1FFFF);
                    d1 = (int)((p1 >> 17) & 0x1FFFF);
                    o1 = (int)(p1 >> 34);
                }
                do_pair(s0, d0, o0, s1, d1, o1, has1);
            }
        }
    } else {
        const int gw = (blockIdx.x * 256 + threadIdx.x) >> 6;
        const int stride = gridDim.x * 32;
        for (int e0 = gw * 8 + slot * 2; e0 < NEDGES; e0 += stride) {
            int s0 = eget(e32, iflag, 0, e0);
            int d0 = eget(e32, iflag, 1, e0);
            bool has1 = (e0 + 1 < NEDGES);
            int s1 = 0, d1 = 0, o1 = 0;
            if (has1) {
                s1 = eget(e32, iflag, 0, e0 + 1);
                d1 = eget(e32, iflag, 1, e0 + 1);
                o1 = e0 + 1;
            }
            do_pair(s0, d0, e0, s1, d1, o1, has1);
        }
    }
}

__global__ void gout_kernel(const float* gsum, float* out) {
    int f = threadIdx.x;
    out[GEMB_OFF + f] = gsum[f] * (1.f / (float)NNODES);
}

extern "C" __attribute__((visibility("default")))
void kernel_launch(void* const* d_in, const int* in_sizes, int n_in,
                   void* d_out, int out_size, void* d_ws, size_t ws_size,
                   hipStream_t stream) {
    const void* x      = d_in[0];
    const int*  eidx   = (const int*)d_in[1];
    const void* W_emb  = d_in[2];
    const void* b_emb  = d_in[3];
    const void* gat_W  = d_in[4];
    const void* gat_as = d_in[5];
    const void* gat_ad = d_in[6];
    const void* gat_b  = d_in[7];
    const void* Wn1    = d_in[8];
    const void* bn1    = d_in[9];
    const void* Wn2    = d_in[10];
    const void* bn2    = d_in[11];
    const void* We1    = d_in[12];
    const void* be1    = d_in[13];
    const void* We2    = d_in[14];
    const void* be2    = d_in[15];
    float* out = (float*)d_out;   // output dtype: float32

    char* ws = (char*)d_ws;
    unsigned short* h       = (unsigned short*)(ws);                // 12.8 MB
    unsigned short* xw      = (unsigned short*)(ws + 12800000);     // 12.8 MB
    float*          alpha_s = (float*)(ws + 25600000);              // 200 KB
    float*          alpha_d = (float*)(ws + 25800000);              // 200 KB
    int*            cnt     = (int*)(ws + 26000000);                // 200 KB
    int*            off     = (int*)(ws + 26200000);                // 200 KB
    int*            bsum    = (int*)(ws + 26400000);                // 1 KB
    float*          gsum    = (float*)(ws + 26401024);              // 512 B
    int*            iflag   = (int*)(ws + 26401536);
    int*            fflag   = (int*)(ws + 26401540);
    u64*            csrp    = (u64*)(ws + 26608000);                // 6.4 MB (dst-grouped)
    int*            cur     = (int*)alpha_s;                        // dead until layer loop
    int*            bcnt    = (int*)(ws + 25600000);                // 800 KB (64x3125)
    u64*            csrb    = (u64*)(ws + 29808000);                // 6.4 MB -> 36.208 MB
    int*            bsum2   = (int*)(ws + 29808000);                // 782 ints, pre-scatter only
    unsigned short* Bsc     = (unsigned short*)out;                 // 12.8 MB scratch

    const int use_pack = (ws_size >= (size_t)33008000) ? 1 : 0;
    const int use_big  = (ws_size >= (size_t)36208000) ? 1 : 0;

    const int node_blks = (NNODES + 255) / 256;    // 196
    const int edge_blks = (NEDGES + 255) / 256;    // 3125
    const int g64       = (NNODES + 63) / 64;      // 782

    init_kernel<<<node_blks, 256, 0, stream>>>(cnt, cur, gsum, iflag);
    detect_kernel<<<2, 256, 0, stream>>>((const unsigned short*)x, eidx, fflag, iflag);

    // embedding: h = relu(x @ W_emb + b_emb)
    gemm_mfma_kernel<<<g64, 256, 0, stream>>>(
        x, 1, W_emb, 0, b_emb, h, NNODES, 1, fflag,
        (float*)0, (float*)0, (const void*)0, (const void*)0, 0);

    // dst-grouped CSR (for aggregation)
    count_kernel<<<edge_blks, 256, 0, stream>>>(eidx, iflag, cnt);
    scan1_kernel<<<node_blks, 256, 0, stream>>>(cnt, off, bsum);
    bscan_kernel<<<1, 1024, 0, stream>>>(bsum, node_blks);
    scan3_kernel<<<node_blks, 256, 0, stream>>>(off, bsum);
    fill_kernel<<<edge_blks, 256, 0, stream>>>(eidx, iflag, off, cur, csrp, use_pack);

    for (int l = 0; l < NLAYERS; l++) {
        gemm_mfma_kernel<<<g64, 256, 0, stream>>>(
            h, 0, gat_W, (size_t)l * HDIM * HDIM, (const void*)0, xw, NNODES, 0, fflag,
            alpha_s, alpha_d, gat_as, gat_ad, l * HDIM);
        aggregate_kernel<<<(NNODES + 3) / 4, 256, 0, stream>>>(
            xw, alpha_s, alpha_d, off, csrp, use_pack, gat_b, l * HDIM, h, fflag);
    }

    // 64-bucket edge partition (alpha/cnt/off + csrp now dead)
    if (use_big) {
        hist_kernel<<<3125, 256, 0, stream>>>(eidx, iflag, bcnt);
        gscan1_kernel<<<782, 256, 0, stream>>>(bcnt, 200000, bsum2);
        bscan_kernel<<<1, 1024, 0, stream>>>(bsum2, 782);
        gscan3_kernel<<<782, 256, 0, stream>>>(bcnt, 200000, bsum2);
        scatter_kernel<<<3125, 256, 0, stream>>>(eidx, iflag, bcnt, csrb);
    }

    // edge pipeline: A -> xw, B -> out-region scratch (h untouched)
    edge_ab_kernel<<<g64, 256, 0, stream>>>(
        h, We1, be1, xw, Bsc, NNODES, fflag);
    edge_split_kernel<<<2048, 256, 0, stream>>>(
        xw, Bsc, eidx, iflag, csrb, bcnt, use_big, We2, be2,
        out + NODE_OUT_ELEMS, fflag);

    // node MLP last (h intact; overwrites the B scratch region) + gsum
    node_mlp_kernel<<<g64, 256, 0, stream>>>(
        h, Wn1, bn1, Wn2, bn2, out, gsum, NNODES, fflag);
    gout_kernel<<<1, 128, 0, stream>>>(gsum, out);
}

// Round 16
// 522.753 us; speedup vs baseline: 1.2526x; 1.0517x over previous
//
#include <hip/hip_runtime.h>

#define NNODES 50000
#define NEDGES 800000
#define HDIM 128
#define DOUT 64
#define NLAYERS 3
#define NEG_SLOPE 0.2f

#define NODE_OUT_ELEMS (NNODES * DOUT)             // 3,200,000
#define EDGE_OUT_ELEMS (NEDGES * 3)                // 2,400,000
#define GEMB_OFF (NODE_OUT_ELEMS + EDGE_OUT_ELEMS) // 5,600,000

typedef __attribute__((ext_vector_type(8))) short short8;
typedef __attribute__((ext_vector_type(4))) float f32x4;
typedef unsigned long long u64;

__device__ __forceinline__ float bf2f(unsigned short u) {
    union { unsigned int i; float f; } v; v.i = ((unsigned int)u) << 16; return v.f;
}
__device__ __forceinline__ unsigned short f2bf(float f) {
    union { unsigned int i; float f; } v; v.f = f;
    unsigned int b = v.i;
    unsigned int r = (b + 0x7FFFu + ((b >> 16) & 1u)) >> 16;
    return (unsigned short)r;
}
__device__ __forceinline__ float leaky(float x) { return x > 0.f ? x : NEG_SLOPE * x; }
// Dual-dtype weight read: raw input pointer, no cvt copy needed.
__device__ __forceinline__ float wread(const void* p, size_t i, int f32) {
    return f32 ? ((const float*)p)[i] : bf2f(((const unsigned short*)p)[i]);
}

// Edge fetch: which=0 -> src, which=1 -> dst. iflag=1 -> int32, 0 -> int64.
__device__ __forceinline__ int eget(const int* e32, const int* iflag, int which, int e) {
    int idx = which * NEDGES + e;
    return (*iflag) ? e32[idx] : e32[2 * idx];
}

// Zero cnt, cur, gsum, flags in one launch.
__global__ void init_kernel(int* cnt, int* cur, float* gsum, int* flags) {
    int i = blockIdx.x * 256 + threadIdx.x;
    if (i < NNODES) { cnt[i] = 0; cur[i] = 0; }
    if (blockIdx.x == 0) {
        if (threadIdx.x < HDIM) gsum[threadIdx.x] = 0.f;
        if (threadIdx.x < 2) flags[threadIdx.x] = 0;
    }
}

// block 0: sampled f32 detect on x; block 1: sampled i64 detect on edges.
__global__ void detect_kernel(const unsigned short* xb, const int* e32,
                              int* fflag, int* iflag) {
    if (blockIdx.x == 0) {
        int hit = 0;
        for (int j = threadIdx.x; j < 4096; j += 256) {
            int e = (xb[j] >> 7) & 0xFF;
            if (e >= 0x90) hit = 1;
        }
        if (hit) atomicOr(fflag, 1);
    } else {
        int hit = 0;
        for (int t = threadIdx.x; t < 16384; t += 256) {
            int i = t * 48;                   // 16383*48 = 786384 < NEDGES
            if (e32[2 * i + 1] != 0) hit = 1;
        }
        if (__any(hit)) {
            if ((threadIdx.x & 63) == 0) atomicOr(iflag, 1);
        }
    }
}

// Parallel single-block exclusive scan, n <= 1024 (replaces the serial
// scan2; at n=196 the serial version cost ~20 us).
__global__ void bscan_kernel(int* a, int n) {
    __shared__ int s[1024];
    int t = threadIdx.x;
    int v = (t < n) ? a[t] : 0;
    s[t] = v;
    __syncthreads();
    for (int d = 1; d < 1024; d <<= 1) {
        int add = (t >= d) ? s[t - d] : 0;
        __syncthreads();
        s[t] += add;
        __syncthreads();
    }
    if (t < n) a[t] = s[t] - v;   // exclusive
}

// ---------------------------------------------------------------------------
// MFMA GEMM, N=128: C_bf16[M,128] = op(A @ Bw[128,128] + bias).
// a_from_x: A may be the raw f32 input — staging converts f32->bf16 in-LDS.
// Fused alpha (layer GEMMs, alpha_s != null): alpha from the PRE-ROUNDING
// f32 accumulators; 16-lane shfl reduce + LDS cross-wave partials.
// ---------------------------------------------------------------------------
__global__ __launch_bounds__(256) void gemm_mfma_kernel(
    const void* __restrict__ Av, int a_from_x, const void* __restrict__ Bw,
    size_t b_off, const void* __restrict__ bias, unsigned short* __restrict__ C,
    int M, int relu, const int* __restrict__ f32flag,
    float* __restrict__ alpha_s, float* __restrict__ alpha_d,
    const void* __restrict__ gat_as, const void* __restrict__ gat_ad, int aoff)
{
    constexpr int KP = 128 + 8;
    __shared__ unsigned short sA[64 * KP];
    __shared__ float pS[64][4], pD[64][4];
    const int f32 = *f32flag;
    const int tid = threadIdx.x;
    const int row0 = blockIdx.x * 64;

    if (a_from_x && f32) {
        const float* Af = (const float*)Av;
        for (int c = tid; c < 64 * 16; c += 256) {
            int r = c >> 4, cp = c & 15;
            int gr = row0 + r;
            unsigned short o[8] = {0, 0, 0, 0, 0, 0, 0, 0};
            if (gr < M) {
                float4 v0 = *(const float4*)(Af + (size_t)gr * 128 + cp * 8);
                float4 v1 = *(const float4*)(Af + (size_t)gr * 128 + cp * 8 + 4);
                o[0] = f2bf(v0.x); o[1] = f2bf(v0.y); o[2] = f2bf(v0.z); o[3] = f2bf(v0.w);
                o[4] = f2bf(v1.x); o[5] = f2bf(v1.y); o[6] = f2bf(v1.z); o[7] = f2bf(v1.w);
            }
            *(uint4*)(&sA[r * KP + cp * 8]) = *(uint4*)o;
        }
    } else {
        const unsigned short* A = (const unsigned short*)Av;
        for (int c = tid; c < 64 * 16; c += 256) {
            int r = c >> 4, cp = c & 15;
            int gr = row0 + r;
            uint4 v = {0u, 0u, 0u, 0u};
            if (gr < M) v = *(const uint4*)(A + (size_t)gr * 128 + cp * 8);
            *(uint4*)(&sA[r * KP + cp * 8]) = v;
        }
    }
    __syncthreads();

    const int wave = tid >> 6, lane = tid & 63;
    const int quad = lane >> 4, l15 = lane & 15;
    const int ncol0 = wave * 32;

    short8 bw[4][2];
    #pragma unroll
    for (int kk = 0; kk < 4; kk++)
        #pragma unroll
        for (int nt = 0; nt < 2; nt++) {
            int n = ncol0 + nt * 16 + l15;
            short8 t;
            #pragma unroll
            for (int j = 0; j < 8; j++)
                t[j] = (short)f2bf(wread(Bw, b_off + (size_t)(kk * 32 + quad * 8 + j) * 128 + n, f32));
            bw[kk][nt] = t;
        }

    float bv[2];
    #pragma unroll
    for (int nt = 0; nt < 2; nt++)
        bv[nt] = bias ? wread(bias, ncol0 + nt * 16 + l15, f32) : 0.f;

    f32x4 acc[4][2];
    #pragma unroll
    for (int mt = 0; mt < 4; mt++)
        #pragma unroll
        for (int nt = 0; nt < 2; nt++) {
            acc[mt][nt][0] = bv[nt]; acc[mt][nt][1] = bv[nt];
            acc[mt][nt][2] = bv[nt]; acc[mt][nt][3] = bv[nt];
        }

    #pragma unroll
    for (int kk = 0; kk < 4; kk++) {
        short8 a[4];
        #pragma unroll
        for (int mt = 0; mt < 4; mt++)
            a[mt] = *(const short8*)(&sA[(mt * 16 + l15) * KP + kk * 32 + quad * 8]);
        #pragma unroll
        for (int mt = 0; mt < 4; mt++)
            #pragma unroll
            for (int nt = 0; nt < 2; nt++)
                acc[mt][nt] = __builtin_amdgcn_mfma_f32_16x16x32_bf16(
                    a[mt], bw[kk][nt], acc[mt][nt], 0, 0, 0);
    }

    // fused alpha from pre-rounding f32 accumulators (wave-uniform branch)
    if (alpha_s) {
        float as0 = wread(gat_as, (size_t)aoff + ncol0 + l15, f32);
        float as1 = wread(gat_as, (size_t)aoff + ncol0 + 16 + l15, f32);
        float ad0 = wread(gat_ad, (size_t)aoff + ncol0 + l15, f32);
        float ad1 = wread(gat_ad, (size_t)aoff + ncol0 + 16 + l15, f32);
        #pragma unroll
        for (int mt = 0; mt < 4; mt++)
            #pragma unroll
            for (int q = 0; q < 4; q++) {
                float vs = acc[mt][0][q] * as0 + acc[mt][1][q] * as1;
                float vd = acc[mt][0][q] * ad0 + acc[mt][1][q] * ad1;
                #pragma unroll
                for (int d = 1; d < 16; d <<= 1) {
                    vs += __shfl_xor(vs, d);
                    vd += __shfl_xor(vd, d);
                }
                if (l15 == 0) {
                    int r = mt * 16 + quad * 4 + q;
                    pS[r][wave] = vs; pD[r][wave] = vd;
                }
            }
        __syncthreads();
        if (tid < 64) {
            int row = row0 + tid;
            if (row < M) {
                alpha_s[row] = pS[tid][0] + pS[tid][1] + pS[tid][2] + pS[tid][3];
                alpha_d[row] = pD[tid][0] + pD[tid][1] + pD[tid][2] + pD[tid][3];
            }
        }
    }

    #pragma unroll
    for (int mt = 0; mt < 4; mt++)
        #pragma unroll
        for (int nt = 0; nt < 2; nt++)
            #pragma unroll
            for (int q = 0; q < 4; q++) {
                int row = row0 + mt * 16 + quad * 4 + q;
                if (row < M) {
                    float v = acc[mt][nt][q];
                    if (relu) v = fmaxf(v, 0.f);
                    C[(size_t)row * 128 + ncol0 + nt * 16 + l15] = f2bf(v);
                }
            }
}

// ---------------------------------------------------------------------------
// Fused node MLP: out = relu(h@Wn1+bn1)@Wn2+bn2, t in LDS. Also accumulates
// the graph-embedding sum from the staged h rows. Round-11 proven.
// ---------------------------------------------------------------------------
__global__ __launch_bounds__(256) void node_mlp_kernel(
    const unsigned short* __restrict__ h, const void* __restrict__ Wn1,
    const void* __restrict__ bn1, const void* __restrict__ Wn2,
    const void* __restrict__ bn2, float* __restrict__ out,
    float* __restrict__ gsum, int M, const int* __restrict__ f32flag)
{
    constexpr int KP = 128 + 8;
    __shared__ unsigned short sA[64 * KP];
    const int f32 = *f32flag;
    const int tid = threadIdx.x;
    const int row0 = blockIdx.x * 64;

    for (int c = tid; c < 64 * 16; c += 256) {
        int r = c >> 4, cp = c & 15;
        int gr = row0 + r;
        uint4 v = {0u, 0u, 0u, 0u};
        if (gr < M) v = *(const uint4*)(h + (size_t)gr * 128 + cp * 8);
        *(uint4*)(&sA[r * KP + cp * 8]) = v;
    }
    __syncthreads();

    // graph-embedding partial from staged rows (oob rows staged as 0).
    if (tid < 128) {
        float hs = 0.f;
        for (int r = 0; r < 64; r++) hs += bf2f(sA[r * KP + tid]);
        atomicAdd(&gsum[tid], hs);
    }

    const int wave = tid >> 6, lane = tid & 63;
    const int quad = lane >> 4, l15 = lane & 15;
    const int ncol0 = wave * 32;

    // ---- GEMM1: t = relu(h @ Wn1 + bn1), N=128 ----
    {
        short8 bw[4][2];
        #pragma unroll
        for (int kk = 0; kk < 4; kk++)
            #pragma unroll
            for (int nt = 0; nt < 2; nt++) {
                int n = ncol0 + nt * 16 + l15;
                short8 t;
                #pragma unroll
                for (int j = 0; j < 8; j++)
                    t[j] = (short)f2bf(wread(Wn1, (size_t)(kk * 32 + quad * 8 + j) * 128 + n, f32));
                bw[kk][nt] = t;
            }
        float bv[2];
        #pragma unroll
        for (int nt = 0; nt < 2; nt++)
            bv[nt] = wread(bn1, ncol0 + nt * 16 + l15, f32);

        f32x4 acc[4][2];
        #pragma unroll
        for (int mt = 0; mt < 4; mt++)
            #pragma unroll
            for (int nt = 0; nt < 2; nt++) {
                acc[mt][nt][0] = bv[nt]; acc[mt][nt][1] = bv[nt];
                acc[mt][nt][2] = bv[nt]; acc[mt][nt][3] = bv[nt];
            }
        #pragma unroll
        for (int kk = 0; kk < 4; kk++) {
            short8 a[4];
            #pragma unroll
            for (int mt = 0; mt < 4; mt++)
                a[mt] = *(const short8*)(&sA[(mt * 16 + l15) * KP + kk * 32 + quad * 8]);
            #pragma unroll
            for (int mt = 0; mt < 4; mt++)
                #pragma unroll
                for (int nt = 0; nt < 2; nt++)
                    acc[mt][nt] = __builtin_amdgcn_mfma_f32_16x16x32_bf16(
                        a[mt], bw[kk][nt], acc[mt][nt], 0, 0, 0);
        }
        __syncthreads();
        #pragma unroll
        for (int mt = 0; mt < 4; mt++)
            #pragma unroll
            for (int nt = 0; nt < 2; nt++)
                #pragma unroll
                for (int q = 0; q < 4; q++) {
                    int r = mt * 16 + quad * 4 + q;
                    sA[r * KP + ncol0 + nt * 16 + l15] =
                        f2bf(fmaxf(acc[mt][nt][q], 0.f));
                }
        __syncthreads();
    }

    // ---- GEMM2: out = t @ Wn2 + bn2, N=64 ----
    {
        const int col = wave * 16 + l15;
        short8 bw[4];
        #pragma unroll
        for (int kk = 0; kk < 4; kk++) {
            short8 t;
            #pragma unroll
            for (int j = 0; j < 8; j++)
                t[j] = (short)f2bf(wread(Wn2, (size_t)(kk * 32 + quad * 8 + j) * 64 + col, f32));
            bw[kk] = t;
        }
        float bv = wread(bn2, col, f32);
        f32x4 acc[4];
        #pragma unroll
        for (int mt = 0; mt < 4; mt++) {
            acc[mt][0] = bv; acc[mt][1] = bv; acc[mt][2] = bv; acc[mt][3] = bv;
        }
        #pragma unroll
        for (int kk = 0; kk < 4; kk++) {
            short8 a[4];
            #pragma unroll
            for (int mt = 0; mt < 4; mt++)
                a[mt] = *(const short8*)(&sA[(mt * 16 + l15) * KP + kk * 32 + quad * 8]);
            #pragma unroll
            for (int mt = 0; mt < 4; mt++)
                acc[mt] = __builtin_amdgcn_mfma_f32_16x16x32_bf16(
                    a[mt], bw[kk], acc[mt], 0, 0, 0);
        }
        #pragma unroll
        for (int mt = 0; mt < 4; mt++)
            #pragma unroll
            for (int q = 0; q < 4; q++) {
                int row = row0 + mt * 16 + quad * 4 + q;
                if (row < M) out[(size_t)row * 64 + col] = acc[mt][q];
            }
    }
}

// ---------------------------------------------------------------------------
// Fused edge A/B: A = h@We1_top + be1 -> Axw; B = h@We1_bot -> Bh (in place
// over h; block writes only rows it staged). Round-11 proven.
// ---------------------------------------------------------------------------
__global__ __launch_bounds__(256) void edge_ab_kernel(
    const unsigned short* __restrict__ h, const void* __restrict__ We1,
    const void* __restrict__ be1, unsigned short* __restrict__ Axw,
    unsigned short* __restrict__ Bh, int M, const int* __restrict__ f32flag)
{
    constexpr int KP = 128 + 8;
    __shared__ unsigned short sA[64 * KP];
    const int f32 = *f32flag;
    const int tid = threadIdx.x;
    const int row0 = blockIdx.x * 64;

    for (int c = tid; c < 64 * 16; c += 256) {
        int r = c >> 4, cp = c & 15;
        int gr = row0 + r;
        uint4 v = {0u, 0u, 0u, 0u};
        if (gr < M) v = *(const uint4*)(h + (size_t)gr * 128 + cp * 8);
        *(uint4*)(&sA[r * KP + cp * 8]) = v;
    }
    __syncthreads();

    const int wave = tid >> 6, lane = tid & 63;
    const int quad = lane >> 4, l15 = lane & 15;
    const int ncol0 = wave * 32;

    #pragma unroll
    for (int half = 0; half < 2; half++) {
        const size_t b_off = (size_t)half * 128 * 128;
        unsigned short* Cp = half ? Bh : Axw;

        short8 bw[4][2];
        #pragma unroll
        for (int kk = 0; kk < 4; kk++)
            #pragma unroll
            for (int nt = 0; nt < 2; nt++) {
                int n = ncol0 + nt * 16 + l15;
                short8 t;
                #pragma unroll
                for (int j = 0; j < 8; j++)
                    t[j] = (short)f2bf(wread(We1, b_off + (size_t)(kk * 32 + quad * 8 + j) * 128 + n, f32));
                bw[kk][nt] = t;
            }
        float bv[2];
        #pragma unroll
        for (int nt = 0; nt < 2; nt++)
            bv[nt] = half ? 0.f : wread(be1, ncol0 + nt * 16 + l15, f32);

        f32x4 acc[4][2];
        #pragma unroll
        for (int mt = 0; mt < 4; mt++)
            #pragma unroll
            for (int nt = 0; nt < 2; nt++) {
                acc[mt][nt][0] = bv[nt]; acc[mt][nt][1] = bv[nt];
                acc[mt][nt][2] = bv[nt]; acc[mt][nt][3] = bv[nt];
            }
        #pragma unroll
        for (int kk = 0; kk < 4; kk++) {
            short8 a[4];
            #pragma unroll
            for (int mt = 0; mt < 4; mt++)
                a[mt] = *(const short8*)(&sA[(mt * 16 + l15) * KP + kk * 32 + quad * 8]);
            #pragma unroll
            for (int mt = 0; mt < 4; mt++)
                #pragma unroll
                for (int nt = 0; nt < 2; nt++)
                    acc[mt][nt] = __builtin_amdgcn_mfma_f32_16x16x32_bf16(
                        a[mt], bw[kk][nt], acc[mt][nt], 0, 0, 0);
        }
        #pragma unroll
        for (int mt = 0; mt < 4; mt++)
            #pragma unroll
            for (int nt = 0; nt < 2; nt++)
                #pragma unroll
                for (int q = 0; q < 4; q++) {
                    int row = row0 + mt * 16 + quad * 4 + q;
                    if (row < M)
                        Cp[(size_t)row * 128 + ncol0 + nt * 16 + l15] =
                            f2bf(acc[mt][nt][q]);
                }
    }
}

// ---- CSR build (group edges by dst) ----
__global__ void count_kernel(const int* e32, const int* iflag, int* cnt) {
    int e = blockIdx.x * 256 + threadIdx.x;
    if (e < NEDGES) atomicAdd(&cnt[eget(e32, iflag, 1, e)], 1);
}
__global__ void scan1_kernel(const int* cnt, int* off, int* bsum) {
    __shared__ int s[256];
    int t = threadIdx.x, i = blockIdx.x * 256 + t;
    int v = (i < NNODES) ? cnt[i] : 0;
    s[t] = v;
    __syncthreads();
    for (int d = 1; d < 256; d <<= 1) {
        int add = (t >= d) ? s[t - d] : 0;
        __syncthreads();
        s[t] += add;
        __syncthreads();
    }
    if (i < NNODES) off[i] = s[t] - v;          // exclusive
    if (t == 255) bsum[blockIdx.x] = s[255];
}
__global__ void scan3_kernel(int* off, const int* bsum) {
    int i = blockIdx.x * 256 + threadIdx.x;
    if (i < NNODES) off[i] += bsum[blockIdx.x];
}
// Packed CSR: one 8B scattered store per edge (src|dst<<17|eid<<34).
__global__ void fill_kernel(const int* e32, const int* iflag, const int* off,
                            int* cur, u64* csrp, int use_pack) {
    int e = blockIdx.x * 256 + threadIdx.x;
    if (e < NEDGES) {
        int s = eget(e32, iflag, 0, e);
        int d = eget(e32, iflag, 1, e);
        int p = atomicAdd(&cur[d], 1);
        int pos = off[d] + p;
        if (use_pack)
            csrp[pos] = (u64)s | ((u64)d << 17) | ((u64)e << 34);
        else
            ((int*)csrp)[pos] = s;
    }
}

// GAT aggregation: one wave per node; h = relu(h + agg + b) in place.
// 64 lanes = 4 edge-slots x 16 feature-lanes; idx+alpha prefetched and
// shfl-broadcast; main loop 2-deep software-pipelined (round-11 proven).
__global__ void aggregate_kernel(const unsigned short* __restrict__ xw,
                                 const float* __restrict__ as_, const float* __restrict__ ad_,
                                 const int* __restrict__ off, const u64* __restrict__ csrp,
                                 int use_pack, const void* __restrict__ gat_b, int boff,
                                 unsigned short* __restrict__ h,
                                 const int* __restrict__ f32flag) {
    const int f32 = *f32flag;
    int wave = threadIdx.x >> 6, lane = threadIdx.x & 63;
    int n = blockIdx.x * 4 + wave;
    if (n >= NNODES) return;
    int o0 = off[n];
    int o1 = (n == NNODES - 1) ? NEDGES : off[n + 1];
    int deg = o1 - o0;
    float adn = ad_[n];
    float lself = leaky(as_[n] + adn);

    int deg64 = deg < 64 ? deg : 64;
    int idxv = 0; float av = 0.f;
    if (lane < deg64) {
        idxv = use_pack ? (int)(csrp[o0 + lane] & 0x1FFFF)
                        : ((const int*)csrp)[o0 + lane];
        av = as_[idxv];
    }

    float m = lself;
    if (lane < deg64) m = fmaxf(m, leaky(av + adn));
    for (int i = 64 + lane; i < deg; i += 64) {
        int s = use_pack ? (int)(csrp[o0 + i] & 0x1FFFF)
                         : ((const int*)csrp)[o0 + i];
        m = fmaxf(m, leaky(as_[s] + adn));
    }
    #pragma unroll
    for (int d = 32; d >= 1; d >>= 1) m = fmaxf(m, __shfl_xor(m, d));

    const int slot = lane >> 4;
    const int l15  = lane & 15;
    float denom = 0.f;
    float acc[8];
    #pragma unroll
    for (int k = 0; k < 8; k++) acc[k] = 0.f;

    // 2-deep software-pipelined main loop
    int i0 = slot, i1 = slot + 4;
    int sidx0 = __shfl(idxv, i0 & 63);
    float aval0 = __shfl(av, i0 & 63);
    int sidx1 = __shfl(idxv, i1 & 63);
    float aval1 = __shfl(av, i1 & 63);
    uint4 rv0 = {0u, 0u, 0u, 0u}, rv1 = {0u, 0u, 0u, 0u};
    if (i0 < deg64) rv0 = *(const uint4*)(xw + (size_t)sidx0 * HDIM + l15 * 8);
    if (i1 < deg64) rv1 = *(const uint4*)(xw + (size_t)sidx1 * HDIM + l15 * 8);
    for (int t0 = 0; t0 < deg64; t0 += 4) {
        int i2 = i0 + 8;
        int sidx2 = __shfl(idxv, i2 & 63);
        float aval2 = __shfl(av, i2 & 63);
        uint4 rv2 = {0u, 0u, 0u, 0u};
        if (i2 < deg64)
            rv2 = *(const uint4*)(xw + (size_t)sidx2 * HDIM + l15 * 8);
        if (i0 < deg64) {
            float p = __expf(leaky(aval0 + adn) - m);
            denom += p;
            const unsigned short* rp = (const unsigned short*)&rv0;
            #pragma unroll
            for (int k = 0; k < 8; k++) acc[k] += p * bf2f(rp[k]);
        }
        i0 = i1; aval0 = aval1; rv0 = rv1;
        i1 = i2; aval1 = aval2; rv1 = rv2;
    }
    // tail (deg > 64), rare
    for (int i = 64 + slot; i < deg; i += 4) {
        int s = use_pack ? (int)(csrp[o0 + i] & 0x1FFFF)
                         : ((const int*)csrp)[o0 + i];
        float p = __expf(leaky(as_[s] + adn) - m);
        denom += p;
        uint4 rv = *(const uint4*)(xw + (size_t)s * HDIM + l15 * 8);
        const unsigned short* rp = (const unsigned short*)&rv;
        #pragma unroll
        for (int k = 0; k < 8; k++) acc[k] += p * bf2f(rp[k]);
    }

    #pragma unroll
    for (int d = 16; d <= 32; d <<= 1) {
        denom += __shfl_xor(denom, d);
        #pragma unroll
        for (int k = 0; k < 8; k++) acc[k] += __shfl_xor(acc[k], d);
    }

    float ps = __expf(lself - m);
    denom += ps;
    uint4 sv = *(const uint4*)(xw + (size_t)n * HDIM + l15 * 8);
    const unsigned short* sp = (const unsigned short*)&sv;
    #pragma unroll
    for (int k = 0; k < 8; k++) acc[k] += ps * bf2f(sp[k]);

    if (slot == 0) {
        float inv = 1.f / denom;
        size_t base = (size_t)n * HDIM + l15 * 8;
        uint4 hv = *(const uint4*)(h + base);
        const unsigned short* hp = (const unsigned short*)&hv;
        unsigned short outv[8];
        #pragma unroll
        for (int k = 0; k < 8; k++) {
            float hx = bf2f(hp[k]);
            float bx = wread(gat_b, boff + l15 * 8 + k, f32);
            outv[k] = f2bf(fmaxf(hx + acc[k] * inv + bx, 0.f));
        }
        *(uint4*)(h + base) = *(uint4*)outv;
    }
}

// ---------------------------------------------------------------------------
// Edge MLP final: per edge v = relu(A[src]+B[dst]); out = v @ We2 + be2.
// Plain 2x unroll per slot (round-9/round-11 proven best: 62.6 us; 4x
// unroll, deeper SWP, and 2D XCD tiling all measured worse).
// ---------------------------------------------------------------------------
__global__ __launch_bounds__(256) void edge_split_kernel(
    const unsigned short* __restrict__ A, const unsigned short* __restrict__ B,
    const int* __restrict__ e32, const int* __restrict__ iflag,
    const u64* __restrict__ csrp, int use_pack,
    const void* __restrict__ We2, const void* __restrict__ be2,
    float* __restrict__ eout, const int* __restrict__ f32flag)
{
    const int f32 = *f32flag;
    const int lane = threadIdx.x & 63;
    const int slot = lane >> 4, l15 = lane & 15;

    float w2[8][3];
    #pragma unroll
    for (int j = 0; j < 8; j++)
        #pragma unroll
        for (int c = 0; c < 3; c++)
            w2[j][c] = wread(We2, (l15 * 8 + j) * 3 + c, f32);
    const float bo0 = wread(be2, 0, f32);
    const float bo1 = wread(be2, 1, f32);
    const float bo2 = wread(be2, 2, f32);

    const int gw = (blockIdx.x * 256 + threadIdx.x) >> 6;
    const int stride = gridDim.x * 32;            // 4 waves/block x 8 edges
    for (int e0 = gw * 8 + slot * 2; e0 < NEDGES; e0 += stride) {
        const int e1 = e0 + 1;
        const bool has1 = (e1 < NEDGES);
        int s0, d0, oe0, s1 = 0, d1 = 0, oe1 = 0;
        if (use_pack) {
            u64 pk0 = csrp[e0];
            s0 = (int)(pk0 & 0x1FFFF); d0 = (int)((pk0 >> 17) & 0x1FFFF);
            oe0 = (int)(pk0 >> 34);
            if (has1) {
                u64 pk1 = csrp[e1];
                s1 = (int)(pk1 & 0x1FFFF); d1 = (int)((pk1 >> 17) & 0x1FFFF);
                oe1 = (int)(pk1 >> 34);
            }
        } else {
            s0 = eget(e32, iflag, 0, e0); d0 = eget(e32, iflag, 1, e0); oe0 = e0;
            if (has1) {
                s1 = eget(e32, iflag, 0, e1); d1 = eget(e32, iflag, 1, e1); oe1 = e1;
            }
        }
        uint4 a0 = *(const uint4*)(A + (size_t)s0 * HDIM + l15 * 8);
        uint4 b0 = *(const uint4*)(B + (size_t)d0 * HDIM + l15 * 8);
        uint4 a1 = {0u, 0u, 0u, 0u}, b1 = {0u, 0u, 0u, 0u};
        if (has1) {
            a1 = *(const uint4*)(A + (size_t)s1 * HDIM + l15 * 8);
            b1 = *(const uint4*)(B + (size_t)d1 * HDIM + l15 * 8);
        }
        const unsigned short* ap0 = (const unsigned short*)&a0;
        const unsigned short* bp0 = (const unsigned short*)&b0;
        const unsigned short* ap1 = (const unsigned short*)&a1;
        const unsigned short* bp1 = (const unsigned short*)&b1;
        float s00 = 0.f, s01 = 0.f, s02 = 0.f;
        float s10 = 0.f, s11 = 0.f, s12 = 0.f;
        #pragma unroll
        for (int j = 0; j < 8; j++) {
            float v0 = fmaxf(bf2f(ap0[j]) + bf2f(bp0[j]), 0.f);
            float v1 = fmaxf(bf2f(ap1[j]) + bf2f(bp1[j]), 0.f);
            s00 += v0 * w2[j][0]; s01 += v0 * w2[j][1]; s02 += v0 * w2[j][2];
            s10 += v1 * w2[j][0]; s11 += v1 * w2[j][1]; s12 += v1 * w2[j][2];
        }
        #pragma unroll
        for (int dd = 1; dd < 16; dd <<= 1) {
            s00 += __shfl_xor(s00, dd); s01 += __shfl_xor(s01, dd); s02 += __shfl_xor(s02, dd);
            s10 += __shfl_xor(s10, dd); s11 += __shfl_xor(s11, dd); s12 += __shfl_xor(s12, dd);
        }
        if (l15 == 0) {
            eout[(size_t)oe0 * 3 + 0] = s00 + bo0;
            eout[(size_t)oe0 * 3 + 1] = s01 + bo1;
            eout[(size_t)oe0 * 3 + 2] = s02 + bo2;
            if (has1) {
                eout[(size_t)oe1 * 3 + 0] = s10 + bo0;
                eout[(size_t)oe1 * 3 + 1] = s11 + bo1;
                eout[(size_t)oe1 * 3 + 2] = s12 + bo2;
            }
        }
    }
}

__global__ void gout_kernel(const float* gsum, float* out) {
    int f = threadIdx.x;
    out[GEMB_OFF + f] = gsum[f] * (1.f / (float)NNODES);
}

extern "C" __attribute__((visibility("default")))
void kernel_launch(void* const* d_in, const int* in_sizes, int n_in,
                   void* d_out, int out_size, void* d_ws, size_t ws_size,
                   hipStream_t stream) {
    const void* x      = d_in[0];
    const int*  eidx   = (const int*)d_in[1];
    const void* W_emb  = d_in[2];
    const void* b_emb  = d_in[3];
    const void* gat_W  = d_in[4];
    const void* gat_as = d_in[5];
    const void* gat_ad = d_in[6];
    const void* gat_b  = d_in[7];
    const void* Wn1    = d_in[8];
    const void* bn1    = d_in[9];
    const void* Wn2    = d_in[10];
    const void* bn2    = d_in[11];
    const void* We1    = d_in[12];
    const void* be1    = d_in[13];
    const void* We2    = d_in[14];
    const void* be2    = d_in[15];
    float* out = (float*)d_out;   // output dtype: float32

    char* ws = (char*)d_ws;
    unsigned short* h       = (unsigned short*)(ws);                // 12.8 MB
    unsigned short* xw      = (unsigned short*)(ws + 12800000);     // 12.8 MB
    float*          alpha_s = (float*)(ws + 25600000);              // 200 KB (cur before loop)
    float*          alpha_d = (float*)(ws + 25800000);              // 200 KB
    int*            cnt     = (int*)(ws + 26000000);                // 200 KB
    int*            off     = (int*)(ws + 26200000);                // 200 KB
    int*            bsum    = (int*)(ws + 26400000);                // 1 KB
    float*          gsum    = (float*)(ws + 26401024);              // 512 B
    int*            iflag   = (int*)(ws + 26401536);
    int*            fflag   = (int*)(ws + 26401540);
    u64*            csrp    = (u64*)(ws + 26608000);                // 6.4 MB -> 33.0 MB
    int*            cur     = (int*)alpha_s;                        // dead until layer loop

    const int use_pack = (ws_size >= (size_t)33008000) ? 1 : 0;

    const int node_blks = (NNODES + 255) / 256;    // 196
    const int edge_blks = (NEDGES + 255) / 256;    // 3125
    const int g64       = (NNODES + 63) / 64;      // 782

    init_kernel<<<node_blks, 256, 0, stream>>>(cnt, cur, gsum, iflag);
    detect_kernel<<<2, 256, 0, stream>>>((const unsigned short*)x, eidx, fflag, iflag);

    // embedding: h = relu(x @ W_emb + b_emb); f32->bf16 staged in-kernel.
    gemm_mfma_kernel<<<g64, 256, 0, stream>>>(
        x, 1, W_emb, 0, b_emb, h, NNODES, 1, fflag,
        (float*)0, (float*)0, (const void*)0, (const void*)0, 0);

    // CSR build (once): count -> scan (parallel) -> fill.
    count_kernel<<<edge_blks, 256, 0, stream>>>(eidx, iflag, cnt);
    scan1_kernel<<<node_blks, 256, 0, stream>>>(cnt, off, bsum);
    bscan_kernel<<<1, 1024, 0, stream>>>(bsum, node_blks);
    scan3_kernel<<<node_blks, 256, 0, stream>>>(off, bsum);
    fill_kernel<<<edge_blks, 256, 0, stream>>>(eidx, iflag, off, cur, csrp, use_pack);

    for (int l = 0; l < NLAYERS; l++) {
        // layer GEMM with fused alpha (alpha from pre-rounding f32 acc)
        gemm_mfma_kernel<<<g64, 256, 0, stream>>>(
            h, 0, gat_W, (size_t)l * HDIM * HDIM, (const void*)0, xw, NNODES, 0, fflag,
            alpha_s, alpha_d, gat_as, gat_ad, l * HDIM);
        aggregate_kernel<<<(NNODES + 3) / 4, 256, 0, stream>>>(
            xw, alpha_s, alpha_d, off, csrp, use_pack, gat_b, l * HDIM, h, fflag);
    }

    // fused node MLP (+ graph-embedding sum from staged h)
    node_mlp_kernel<<<g64, 256, 0, stream>>>(
        h, Wn1, bn1, Wn2, bn2, out, gsum, NNODES, fflag);
    gout_kernel<<<1, 128, 0, stream>>>(gsum, out);

    // fused edge A/B GEMMs: A -> xw, B -> h (in place), then final edge MLP.
    edge_ab_kernel<<<g64, 256, 0, stream>>>(
        h, We1, be1, xw, h, NNODES, fflag);
    edge_split_kernel<<<2048, 256, 0, stream>>>(
        xw, h, eidx, iflag, csrp, use_pack, We2, be2,
        out + NODE_OUT_ELEMS, fflag);
}